// Round 5
// baseline (1185.150 us; speedup 1.0000x reference)
//
#include <hip/hip_runtime.h>
#include <hip/hip_bf16.h>

#define T_SEQ 512

typedef __attribute__((ext_vector_type(8))) short frag_ab;
typedef __attribute__((ext_vector_type(4))) float frag_cd;

static __device__ __forceinline__ unsigned short f2bf_rnd(float f){
    union { float f; unsigned u; } v; v.f = f;
    unsigned r = v.u + 0x7fffu + ((v.u >> 16) & 1u);
    return (unsigned short)(r >> 16);
}
static __device__ __forceinline__ float bf2f(unsigned short h){
    union { unsigned u; float f; } v; v.u = ((unsigned)h) << 16;
    return v.f;
}
static __device__ __forceinline__ void tsplit(float f, unsigned short &hi, unsigned short &lo){
    union { float f; unsigned u; } v; v.f = f;
    const unsigned uh = v.u & 0xFFFF0000u;
    hi = (unsigned short)(uh >> 16);
    union { unsigned u; float f; } w; w.u = uh;
    union { float f; unsigned u; } r; r.f = f - w.f;
    lo = (unsigned short)(r.u >> 16);
}
static __device__ __forceinline__ float sigf(float v){
    return __builtin_amdgcn_rcpf(1.0f + __builtin_amdgcn_exp2f(-1.4426950408889634f * v));
}
static __device__ __forceinline__ float tanhf2(float v){
    return 2.0f * __builtin_amdgcn_rcpf(1.0f + __builtin_amdgcn_exp2f(-2.8853900817779268f * v)) - 1.0f;
}
static __device__ __forceinline__ frag_ab loadBfrag(const float* __restrict__ W, int ldk, int jcol, int k0){
    const float* p = W + jcol * ldk + k0;
    frag_ab r;
    #pragma unroll
    for (int i = 0; i < 8; ++i) r[i] = (short)f2bf_rnd(p[i]);
    return r;
}
// select a[q] for runtime q in 0..3 without scratch (cndmask chain)
static __device__ __forceinline__ float sel4(frag_cd a, int q){
    const float v01 = (q == 0) ? a[0] : a[1];
    const float v23 = (q == 2) ? a[2] : a[3];
    return (q < 2) ? v01 : v23;
}

#define MFMA(a,b,c) __builtin_amdgcn_mfma_f32_16x16x32_bf16((a),(b),(c),0,0,0)

// 4 batches/block, 512 blocks -> 2 blocks/CU (2 independent barrier domains
// interleaved per SIMD fill each other's latency bubbles).
// Waves 0-3 ("P"): layer-1, each owns 16 h1-cols; batch rows duplicated x4 in
//   MFMA fragments, gate work deduped to 1 unit/lane (row = lq via cndmask).
// Waves 4-7 ("C"): layer-2 fully in-register (redundant across waves; wave cw
//   owns batch row cw for gates/LDS-writeback) + x staging via depth-3 ring
//   with a register held across one full phase (HBM latency spans a phase).
__global__ __launch_bounds__(512, 4)
void gru_fused4(const float* __restrict__ x,
                const float* __restrict__ Wih1, const float* __restrict__ Whh1,
                const float* __restrict__ bih1, const float* __restrict__ bhh1,
                const float* __restrict__ Wih2, const float* __restrict__ Whh2,
                const float* __restrict__ bih2, const float* __restrict__ bhh2,
                const float* __restrict__ Wfc,  const float* __restrict__ bfc,
                const float* __restrict__ Wout, const float* __restrict__ bout,
                float* __restrict__ out)
{
    __shared__ __align__(16) unsigned short RGhi[2][288], RGlo[2][288];  // h1 ring [slot][row*72+col]
    __shared__ __align__(16) unsigned short XHI[3][288],  XLO[3][288];   // x ring (depth 3)
    __shared__ __align__(16) unsigned short H2HI[2][160], H2LO[2][160];  // h2 ring [slot][row*40+col]
    __shared__ float HFIN[128];
    __shared__ float FCS[64];

    const int tid  = threadIdx.x;
    const int wv   = tid >> 6;
    const int lane = tid & 63;
    const int lrow = lane & 15;
    const int lq   = lane >> 4;
    const int r4   = lrow & 3;
    const bool isP = (wv < 4);
    const int cw   = wv - 4;
    const int bbase = blockIdx.x * 4;

    for (int i = tid; i < 288; i += 512){ RGhi[1][i] = 0; RGlo[1][i] = 0; }
    for (int i = tid; i < 160; i += 512){ H2HI[1][i] = 0; H2LO[1][i] = 0; }

    // prologue: stage x(0) -> slot 0, x(1) -> slot 1 (512 thr x 1 elem)
    {
        const int s = tid >> 8, idx = tid & 255;
        const int b = idx >> 6, k = idx & 63;
        unsigned short hb, lb;
        tsplit(x[((size_t)(bbase + b) * T_SEQ + s) * 64 + k], hb, lb);
        XHI[s][b*72 + k] = hb; XLO[s][b*72 + k] = lb;
    }

    // role-unioned register files
    frag_ab WU[18];
    frag_cd AU[8];
    frag_ab FU[8];
    float   BU[8];
    float   HS[2] = {0.f, 0.f};

    if (isP){
        const int j = wv*16 + lrow;
        #pragma unroll
        for (int g = 0; g < 3; ++g){
            #pragma unroll
            for (int kf = 0; kf < 2; ++kf){
                WU[g*4 + kf]     = loadBfrag(Wih1, 64, g*64 + j, kf*32 + 8*lq);
                WU[g*4 + 2 + kf] = loadBfrag(Whh1, 64, g*64 + j, kf*32 + 8*lq);
            }
        }
        BU[0] = bih1[j]       + bhh1[j];
        BU[1] = bih1[64 + j]  + bhh1[64 + j];
        BU[2] = bih1[128 + j];
        BU[3] = bhh1[128 + j];
    } else {
        #pragma unroll
        for (int b = 0; b < 2; ++b){
            const int c = b*16 + lrow;
            #pragma unroll
            for (int kf = 0; kf < 2; ++kf){
                WU[0 + b*2 + kf] = loadBfrag(Wih2, 64, c,      kf*32 + 8*lq);
                WU[4 + b*2 + kf] = loadBfrag(Wih2, 64, 32 + c, kf*32 + 8*lq);
                WU[8 + b*2 + kf] = loadBfrag(Wih2, 64, 64 + c, kf*32 + 8*lq);
            }
            WU[12 + b] = loadBfrag(Whh2, 32, c,      8*lq);
            WU[14 + b] = loadBfrag(Whh2, 32, 32 + c, 8*lq);
            WU[16 + b] = loadBfrag(Whh2, 32, 64 + c, 8*lq);
            BU[0 + b] = bih2[c]      + bhh2[c];
            BU[2 + b] = bih2[32 + c] + bhh2[32 + c];
            BU[4 + b] = bih2[64 + c];
            BU[6 + b] = bhh2[64 + c];
        }
    }

    const float* xrowp = x + ((size_t)(bbase + (isP ? 0 : cw)) * T_SEQ) * 64 + lane;
    float xpend = 0.f;
    if (!isP) xpend = xrowp[2*64];   // x(2) in flight; consumed at phase 0

    __syncthreads();

    int sr = 0, sw = 2;   // x-ring read/write slots: sr = t%3, sw = (t+2)%3

    for (int t = 0; t <= T_SEQ; ++t){
        const int sCur = t & 1, sPrev = (t + 1) & 1;
        if (isP){
            if (t < T_SEQ){
                #pragma unroll
                for (int kf = 0; kf < 2; ++kf){
                    const int o = r4*72 + kf*32 + 8*lq;
                    FU[0+kf] = *(const frag_ab*)(XHI[sr]    + o);
                    FU[2+kf] = *(const frag_ab*)(XLO[sr]    + o);
                    FU[4+kf] = *(const frag_ab*)(RGhi[sPrev] + o);
                    FU[6+kf] = *(const frag_ab*)(RGlo[sPrev] + o);
                }
                #pragma unroll
                for (int a = 0; a < 4; ++a) AU[a] = frag_cd{0.f,0.f,0.f,0.f};
                #pragma unroll
                for (int kf = 0; kf < 2; ++kf){
                    AU[0] = MFMA(FU[0+kf], WU[0+kf],  AU[0]);
                    AU[0] = MFMA(FU[2+kf], WU[0+kf],  AU[0]);
                    AU[0] = MFMA(FU[4+kf], WU[2+kf],  AU[0]);
                    AU[0] = MFMA(FU[6+kf], WU[2+kf],  AU[0]);
                    AU[1] = MFMA(FU[0+kf], WU[4+kf],  AU[1]);
                    AU[1] = MFMA(FU[2+kf], WU[4+kf],  AU[1]);
                    AU[1] = MFMA(FU[4+kf], WU[6+kf],  AU[1]);
                    AU[1] = MFMA(FU[6+kf], WU[6+kf],  AU[1]);
                    AU[2] = MFMA(FU[0+kf], WU[8+kf],  AU[2]);
                    AU[2] = MFMA(FU[2+kf], WU[8+kf],  AU[2]);
                    AU[3] = MFMA(FU[4+kf], WU[10+kf], AU[3]);
                    AU[3] = MFMA(FU[6+kf], WU[10+kf], AU[3]);
                }
                // 1 gate unit/lane: batch row = lq, col = wv*16+lrow
                const float vR = sel4(AU[0], lq);
                const float vZ = sel4(AU[1], lq);
                const float vI = sel4(AU[2], lq);
                const float vH = sel4(AU[3], lq);
                const float rg = sigf(vR + BU[0]);
                const float zg = sigf(vZ + BU[1]);
                const float ng = tanhf2(vI + BU[2] + rg*(vH + BU[3]));
                const float h  = ng + zg*(HS[0] - ng); HS[0] = h;
                unsigned short hb, lb; tsplit(h, hb, lb);
                const int col = wv*16 + lrow;
                RGhi[sCur][lq*72 + col] = hb;
                RGlo[sCur][lq*72 + col] = lb;
            }
        } else {
            float xnew = 0.f;
            if (t < T_SEQ){
                const int tl = (t + 3 < T_SEQ) ? (t + 3) : (T_SEQ - 1);
                xnew = xrowp[(size_t)tl * 64];      // issue early; consumed next phase
            }
            if (t >= 1){   // layer-2 step t-1, fully in-register
                #pragma unroll
                for (int kf = 0; kf < 2; ++kf){
                    const int o = r4*72 + kf*32 + 8*lq;
                    FU[0+kf] = *(const frag_ab*)(RGhi[sPrev] + o);
                    FU[2+kf] = *(const frag_ab*)(RGlo[sPrev] + o);
                }
                FU[4] = *(const frag_ab*)(H2HI[sCur] + r4*40 + 8*lq);
                FU[5] = *(const frag_ab*)(H2LO[sCur] + r4*40 + 8*lq);
                #pragma unroll
                for (int a = 0; a < 8; ++a) AU[a] = frag_cd{0.f,0.f,0.f,0.f};
                #pragma unroll
                for (int b = 0; b < 2; ++b){
                    #pragma unroll
                    for (int kf = 0; kf < 2; ++kf){
                        AU[0+b] = MFMA(FU[0+kf], WU[0+b*2+kf], AU[0+b]);
                        AU[0+b] = MFMA(FU[2+kf], WU[0+b*2+kf], AU[0+b]);
                        AU[2+b] = MFMA(FU[0+kf], WU[4+b*2+kf], AU[2+b]);
                        AU[2+b] = MFMA(FU[2+kf], WU[4+b*2+kf], AU[2+b]);
                        AU[4+b] = MFMA(FU[0+kf], WU[8+b*2+kf], AU[4+b]);
                        AU[4+b] = MFMA(FU[2+kf], WU[8+b*2+kf], AU[4+b]);
                    }
                    AU[0+b] = MFMA(FU[4], WU[12+b], AU[0+b]);
                    AU[0+b] = MFMA(FU[5], WU[12+b], AU[0+b]);
                    AU[2+b] = MFMA(FU[4], WU[14+b], AU[2+b]);
                    AU[2+b] = MFMA(FU[5], WU[14+b], AU[2+b]);
                    AU[6+b] = MFMA(FU[4], WU[16+b], AU[6+b]);
                    AU[6+b] = MFMA(FU[5], WU[16+b], AU[6+b]);
                }
                const int sW = (t + 1) & 1;       // slot for h2(t-1)
                #pragma unroll
                for (int K = 0; K < 4; ++K) if (cw == K){   // wave-uniform static K
                    #pragma unroll
                    for (int b = 0; b < 2; ++b){
                        const float rv = sigf(AU[0+b][K] + BU[0+b]);
                        const float zv = sigf(AU[2+b][K] + BU[2+b]);
                        const float nv = tanhf2(AU[4+b][K] + BU[4+b] + rv*(AU[6+b][K] + BU[6+b]));
                        const float hn = nv + zv*(HS[b] - nv);
                        HS[b] = hn;
                        if (lq == 0){
                            unsigned short hb, lb; tsplit(hn, hb, lb);
                            H2HI[sW][K*40 + b*16 + lrow] = hb;
                            H2LO[sW][K*40 + b*16 + lrow] = lb;
                        }
                    }
                }
            }
            if (t < T_SEQ){   // write x(t+2) (held across one full phase) into slot sw
                unsigned short hb, lb; tsplit(xpend, hb, lb);
                XHI[sw][cw*72 + lane] = hb;
                XLO[sw][cw*72 + lane] = lb;
                xpend = xnew;
            }
        }
        __syncthreads();
        sr = (sr == 2) ? 0 : sr + 1;
        sw = (sw == 2) ? 0 : sw + 1;
    }

    // head: h2(T-1) is in H2 slot (T_SEQ+1)&1 == 1
    if (tid < 128){
        const int r = tid >> 5, c = tid & 31;
        HFIN[r*32 + c] = bf2f(H2HI[1][r*40 + c]) + bf2f(H2LO[1][r*40 + c]);
    }
    __syncthreads();
    if (tid < 64){
        const int b = tid >> 4, f = tid & 15;
        float s = bfc[f];
        #pragma unroll
        for (int k = 0; k < 32; ++k) s += HFIN[b*32 + k] * Wfc[f*32 + k];
        FCS[b*16 + f] = fmaxf(s, 0.f);
    }
    __syncthreads();
    if (tid < 4){
        float o = bout[0];
        #pragma unroll
        for (int f = 0; f < 16; ++f) o += FCS[tid*16 + f] * Wout[f];
        out[bbase + tid] = o;
    }
}

extern "C" void kernel_launch(void* const* d_in, const int* in_sizes, int n_in,
                              void* d_out, int out_size, void* d_ws, size_t ws_size,
                              hipStream_t stream) {
    const float* x    = (const float*)d_in[0];
    const float* Wih1 = (const float*)d_in[1];
    const float* Whh1 = (const float*)d_in[2];
    const float* bih1 = (const float*)d_in[3];
    const float* bhh1 = (const float*)d_in[4];
    const float* Wih2 = (const float*)d_in[5];
    const float* Whh2 = (const float*)d_in[6];
    const float* bih2 = (const float*)d_in[7];
    const float* bhh2 = (const float*)d_in[8];
    const float* Wfc  = (const float*)d_in[9];
    const float* bfc  = (const float*)d_in[10];
    const float* Wout = (const float*)d_in[11];
    const float* bout = (const float*)d_in[12];

    gru_fused4<<<512, 512, 0, stream>>>(x, Wih1, Whh1, bih1, bhh1,
                                        Wih2, Whh2, bih2, bhh2,
                                        Wfc, bfc, Wout, bout, (float*)d_out);
}

// Round 6
// 508.279 us; speedup vs baseline: 2.3317x; 2.3317x over previous
//
#include <hip/hip_runtime.h>
#include <hip/hip_bf16.h>

#define T_SEQ 512

typedef __attribute__((ext_vector_type(8))) short frag_ab;
typedef __attribute__((ext_vector_type(4))) float frag_cd;

static __device__ __forceinline__ unsigned short f2bf_rnd(float f){
    union { float f; unsigned u; } v; v.f = f;
    unsigned r = v.u + 0x7fffu + ((v.u >> 16) & 1u);
    return (unsigned short)(r >> 16);
}
static __device__ __forceinline__ float bf2f(unsigned short h){
    union { unsigned u; float f; } v; v.u = ((unsigned)h) << 16;
    return v.f;
}
static __device__ __forceinline__ void tsplit(float f, unsigned short &hi, unsigned short &lo){
    union { float f; unsigned u; } v; v.f = f;
    const unsigned uh = v.u & 0xFFFF0000u;
    hi = (unsigned short)(uh >> 16);
    union { unsigned u; float f; } w; w.u = uh;
    union { float f; unsigned u; } r; r.f = f - w.f;
    lo = (unsigned short)(r.u >> 16);
}
static __device__ __forceinline__ float sigf(float v){
    return __builtin_amdgcn_rcpf(1.0f + __builtin_amdgcn_exp2f(-1.4426950408889634f * v));
}
static __device__ __forceinline__ float tanhf2(float v){
    return 2.0f * __builtin_amdgcn_rcpf(1.0f + __builtin_amdgcn_exp2f(-2.8853900817779268f * v)) - 1.0f;
}
static __device__ __forceinline__ frag_ab loadBfrag(const float* __restrict__ W, int ldk, int jcol, int k0){
    const float* p = W + jcol * ldk + k0;
    frag_ab r;
    #pragma unroll
    for (int i = 0; i < 8; ++i) r[i] = (short)f2bf_rnd(p[i]);
    return r;
}
static __device__ __forceinline__ float sel4(frag_cd a, int q){
    const float v01 = (q == 0) ? a[0] : a[1];
    const float v23 = (q == 2) ? a[2] : a[3];
    return (q < 2) ? v01 : v23;
}
static __device__ __forceinline__ frag_cd splat4(float v){ return frag_cd{v,v,v,v}; }

#define MFMA(a,b,c) __builtin_amdgcn_mfma_f32_16x16x32_bf16((a),(b),(c),0,0,0)

// 4 batches/block, 512 blocks -> 2 blocks/CU = two INDEPENDENT barrier domains
// per CU (anti-phase drift fills each other's latency bubbles) at the same
// 8 waves/CU as R4. Every wave does BOTH layers (merged role, ~196 regs/wave,
// launch_bounds(256,2) so no spill):
//   layer-1 for step t on its 16 h1-cols (24 MFMA), then
//   layer-2 for step t-1 on its (col-half, batch-pair) quadrant (18 MFMA,
//   A-fragments shared with hh1's h1(t-1) reads -> no extra LDS traffic).
// Biases ride in the MFMA C-operand (persistent splat frags): no acc-init
// movs, no bias adds in gates. One barrier per step.
__global__ __launch_bounds__(256, 2)
void gru_fused5(const float* __restrict__ x,
                const float* __restrict__ Wih1, const float* __restrict__ Whh1,
                const float* __restrict__ bih1, const float* __restrict__ bhh1,
                const float* __restrict__ Wih2, const float* __restrict__ Whh2,
                const float* __restrict__ bih2, const float* __restrict__ bhh2,
                const float* __restrict__ Wfc,  const float* __restrict__ bfc,
                const float* __restrict__ Wout, const float* __restrict__ bout,
                float* __restrict__ out)
{
    __shared__ __align__(16) unsigned short RGhi[2][288], RGlo[2][288];  // h1 ring: [slot][b*72+col]
    __shared__ __align__(16) unsigned short XHI[3][288],  XLO[3][288];   // x ring (depth 3)
    __shared__ __align__(16) unsigned short H2HI[2][160], H2LO[2][160];  // h2 ring: [slot][b*40+j]
    __shared__ float HFIN[128];
    __shared__ float FCS[64];

    const int tid  = threadIdx.x;
    const int wv   = tid >> 6;         // 0..3
    const int lane = tid & 63;
    const int lrow = lane & 15;
    const int lq   = lane >> 4;
    const int r4   = lrow & 3;
    const int bbase = blockIdx.x * 4;

    for (int i = tid; i < 288; i += 256){ RGhi[1][i] = 0; RGlo[1][i] = 0; }
    for (int i = tid; i < 160; i += 256){ H2HI[1][i] = 0; H2LO[1][i] = 0; }

    // prologue x staging: x(0)->slot0, x(1)->slot1 (256 thr x 1 elem each)
    const int xb = tid >> 6, xk = tid & 63;
    #pragma unroll
    for (int s = 0; s < 2; ++s){
        unsigned short hb, lb;
        tsplit(x[((size_t)(bbase + xb) * T_SEQ + s) * 64 + xk], hb, lb);
        XHI[s][xb*72 + xk] = hb; XLO[s][xb*72 + xk] = lb;
    }

    // ---- persistent weights & bias-splat fragments ----
    const int col1 = wv*16 + lrow;                 // layer-1 unit col
    frag_ab Wr1i[2], Wz1i[2], Wn1i[2], Wr1h[2], Wz1h[2], Wn1h[2];
    #pragma unroll
    for (int kf = 0; kf < 2; ++kf){
        const int k0 = kf*32 + 8*lq;
        Wr1i[kf] = loadBfrag(Wih1, 64, col1,       k0);
        Wz1i[kf] = loadBfrag(Wih1, 64, 64  + col1, k0);
        Wn1i[kf] = loadBfrag(Wih1, 64, 128 + col1, k0);
        Wr1h[kf] = loadBfrag(Whh1, 64, col1,       k0);
        Wz1h[kf] = loadBfrag(Whh1, 64, 64  + col1, k0);
        Wn1h[kf] = loadBfrag(Whh1, 64, 128 + col1, k0);
    }
    const frag_cd BR1 = splat4(bih1[col1] + bhh1[col1]);
    const frag_cd BZ1 = splat4(bih1[64 + col1] + bhh1[64 + col1]);
    const frag_cd BI1 = splat4(bih1[128 + col1]);
    const frag_cd BH1 = splat4(bhh1[128 + col1]);

    const int c2 = (wv & 1)*16 + lrow;             // layer-2 unit col (this wave's half)
    frag_ab Wr2i[2], Wz2i[2], Wn2i[2], Wr2h, Wz2h, Wn2h;
    #pragma unroll
    for (int kf = 0; kf < 2; ++kf){
        const int k0 = kf*32 + 8*lq;
        Wr2i[kf] = loadBfrag(Wih2, 64, c2,      k0);
        Wz2i[kf] = loadBfrag(Wih2, 64, 32 + c2, k0);
        Wn2i[kf] = loadBfrag(Wih2, 64, 64 + c2, k0);
    }
    Wr2h = loadBfrag(Whh2, 32, c2,      8*lq);
    Wz2h = loadBfrag(Whh2, 32, 32 + c2, 8*lq);
    Wn2h = loadBfrag(Whh2, 32, 64 + c2, 8*lq);
    const frag_cd BR2 = splat4(bih2[c2] + bhh2[c2]);
    const frag_cd BZ2 = splat4(bih2[32 + c2] + bhh2[32 + c2]);
    const frag_cd BI2 = splat4(bih2[64 + c2]);
    const frag_cd BH2 = splat4(bhh2[64 + c2]);

    const float* xrowp = x + (size_t)(bbase + xb) * T_SEQ * 64 + xk;
    float xpend = xrowp[2*64];   // x(2) pending

    float hs1 = 0.f;             // h1 state: unit (b=lq, col1)
    float hs2[2] = {0.f, 0.f};   // h2 state: units (b=(wv&2)+u, c2)

    __syncthreads();

    int sr = 0, sw = 2;          // x-ring read/write slots

    for (int t = 0; t <= T_SEQ; ++t){
        const int sCur = t & 1, sPrev = sCur ^ 1;

        frag_ab xh[2], xl[2], hh[2], hl[2], g2h, g2l;
        float xnew = 0.f;
        if (t < T_SEQ){
            const int tl = (t + 3 < T_SEQ) ? (t + 3) : (T_SEQ - 1);
            xnew = xrowp[(size_t)tl * 64];              // in flight across this phase
            #pragma unroll
            for (int kf = 0; kf < 2; ++kf){
                const int o = r4*72 + kf*32 + 8*lq;
                xh[kf] = *(const frag_ab*)(XHI[sr] + o);
                xl[kf] = *(const frag_ab*)(XLO[sr] + o);
            }
        }
        #pragma unroll
        for (int kf = 0; kf < 2; ++kf){                  // h1(t-1): used by L1-hh AND L2-ih
            const int o = r4*72 + kf*32 + 8*lq;
            hh[kf] = *(const frag_ab*)(RGhi[sPrev] + o);
            hl[kf] = *(const frag_ab*)(RGlo[sPrev] + o);
        }
        if (t >= 1){
            const int o2 = r4*40 + 8*lq;
            g2h = *(const frag_ab*)(H2HI[sCur] + o2);    // h2(t-2)
            g2l = *(const frag_ab*)(H2LO[sCur] + o2);
        }

        if (t < T_SEQ){   // ---- layer-1 step t ----
            frag_cd A0 = BR1, A1 = BZ1, A2 = BI1, A3 = BH1;
            #pragma unroll
            for (int kf = 0; kf < 2; ++kf){
                A0 = MFMA(xh[kf], Wr1i[kf], A0);
                A0 = MFMA(xl[kf], Wr1i[kf], A0);
                A0 = MFMA(hh[kf], Wr1h[kf], A0);
                A0 = MFMA(hl[kf], Wr1h[kf], A0);
                A1 = MFMA(xh[kf], Wz1i[kf], A1);
                A1 = MFMA(xl[kf], Wz1i[kf], A1);
                A1 = MFMA(hh[kf], Wz1h[kf], A1);
                A1 = MFMA(hl[kf], Wz1h[kf], A1);
                A2 = MFMA(xh[kf], Wn1i[kf], A2);
                A2 = MFMA(xl[kf], Wn1i[kf], A2);
                A3 = MFMA(hh[kf], Wn1h[kf], A3);
                A3 = MFMA(hl[kf], Wn1h[kf], A3);
            }
            const float vR = sel4(A0, lq);
            const float vZ = sel4(A1, lq);
            const float vI = sel4(A2, lq);
            const float vH = sel4(A3, lq);
            const float rg = sigf(vR);
            const float zg = sigf(vZ);
            const float ng = tanhf2(vI + rg*vH);
            const float h  = ng + zg*(hs1 - ng); hs1 = h;
            unsigned short hb, lb; tsplit(h, hb, lb);
            RGhi[sCur][lq*72 + col1] = hb;
            RGlo[sCur][lq*72 + col1] = lb;
        }

        if (t >= 1){      // ---- layer-2 step t-1 (quadrant: cols c2, batches (wv&2)+{0,1}) ----
            frag_cd B0 = BR2, B1 = BZ2, B2 = BI2, B3 = BH2;
            #pragma unroll
            for (int kf = 0; kf < 2; ++kf){
                B0 = MFMA(hh[kf], Wr2i[kf], B0);
                B0 = MFMA(hl[kf], Wr2i[kf], B0);
                B1 = MFMA(hh[kf], Wz2i[kf], B1);
                B1 = MFMA(hl[kf], Wz2i[kf], B1);
                B2 = MFMA(hh[kf], Wn2i[kf], B2);
                B2 = MFMA(hl[kf], Wn2i[kf], B2);
            }
            B0 = MFMA(g2h, Wr2h, B0);
            B0 = MFMA(g2l, Wr2h, B0);
            B1 = MFMA(g2h, Wz2h, B1);
            B1 = MFMA(g2l, Wz2h, B1);
            B3 = MFMA(g2h, Wn2h, B3);
            B3 = MFMA(g2l, Wn2h, B3);
            // static reg indices via wave-uniform branch (no scratch)
            if ((wv & 2) == 0){
                #pragma unroll
                for (int u = 0; u < 2; ++u){
                    const float rv = sigf(u ? B0[1] : B0[0]);
                    const float zv = sigf(u ? B1[1] : B1[0]);
                    const float nv = tanhf2((u ? B2[1] : B2[0]) + rv*(u ? B3[1] : B3[0]));
                    const float hn = nv + zv*(hs2[u] - nv); hs2[u] = hn;
                    if (lq == 0){
                        unsigned short hb, lb; tsplit(hn, hb, lb);
                        H2HI[sPrev][u*40 + c2] = hb;
                        H2LO[sPrev][u*40 + c2] = lb;
                    }
                }
            } else {
                #pragma unroll
                for (int u = 0; u < 2; ++u){
                    const float rv = sigf(u ? B0[3] : B0[2]);
                    const float zv = sigf(u ? B1[3] : B1[2]);
                    const float nv = tanhf2((u ? B2[3] : B2[2]) + rv*(u ? B3[3] : B3[2]));
                    const float hn = nv + zv*(hs2[u] - nv); hs2[u] = hn;
                    if (lq == 0){
                        unsigned short hb, lb; tsplit(hn, hb, lb);
                        H2HI[sPrev][(2+u)*40 + c2] = hb;
                        H2LO[sPrev][(2+u)*40 + c2] = lb;
                    }
                }
            }
        }

        if (t < T_SEQ){   // write x(t+2) (held since last phase) into ring slot sw
            unsigned short hb, lb; tsplit(xpend, hb, lb);
            XHI[sw][xb*72 + xk] = hb;
            XLO[sw][xb*72 + xk] = lb;
            xpend = xnew;
        }

        __syncthreads();
        sr = (sr == 2) ? 0 : sr + 1;
        sw = (sw == 2) ? 0 : sw + 1;
    }

    // head: h2(T-1) is in H2 ring slot 1 (written at phase T into sPrev=1)
    if (tid < 128){
        const int r = tid >> 5, c = tid & 31;
        HFIN[r*32 + c] = bf2f(H2HI[1][r*40 + c]) + bf2f(H2LO[1][r*40 + c]);
    }
    __syncthreads();
    if (tid < 64){
        const int b = tid >> 4, f = tid & 15;
        float s = bfc[f];
        #pragma unroll
        for (int k = 0; k < 32; ++k) s += HFIN[b*32 + k] * Wfc[f*32 + k];
        FCS[b*16 + f] = fmaxf(s, 0.f);
    }
    __syncthreads();
    if (tid < 4){
        float o = bout[0];
        #pragma unroll
        for (int f = 0; f < 16; ++f) o += FCS[tid*16 + f] * Wout[f];
        out[bbase + tid] = o;
    }
}

extern "C" void kernel_launch(void* const* d_in, const int* in_sizes, int n_in,
                              void* d_out, int out_size, void* d_ws, size_t ws_size,
                              hipStream_t stream) {
    const float* x    = (const float*)d_in[0];
    const float* Wih1 = (const float*)d_in[1];
    const float* Whh1 = (const float*)d_in[2];
    const float* bih1 = (const float*)d_in[3];
    const float* bhh1 = (const float*)d_in[4];
    const float* Wih2 = (const float*)d_in[5];
    const float* Whh2 = (const float*)d_in[6];
    const float* bih2 = (const float*)d_in[7];
    const float* bhh2 = (const float*)d_in[8];
    const float* Wfc  = (const float*)d_in[9];
    const float* bfc  = (const float*)d_in[10];
    const float* Wout = (const float*)d_in[11];
    const float* bout = (const float*)d_in[12];

    gru_fused5<<<512, 256, 0, stream>>>(x, Wih1, Whh1, bih1, bhh1,
                                        Wih2, Whh2, bih2, bhh2,
                                        Wfc, bfc, Wout, bout, (float*)d_out);
}

// Round 7
// 453.383 us; speedup vs baseline: 2.6140x; 1.1211x over previous
//
#include <hip/hip_runtime.h>
#include <hip/hip_bf16.h>

#define T_SEQ 512

typedef __attribute__((ext_vector_type(8))) short frag_ab;
typedef __attribute__((ext_vector_type(4))) float frag_cd;

static __device__ __forceinline__ unsigned short f2bf_rnd(float f){
    union { float f; unsigned u; } v; v.f = f;
    unsigned r = v.u + 0x7fffu + ((v.u >> 16) & 1u);
    return (unsigned short)(r >> 16);
}
static __device__ __forceinline__ float bf2f(unsigned short h){
    union { unsigned u; float f; } v; v.u = ((unsigned)h) << 16;
    return v.f;
}
static __device__ __forceinline__ void tsplit(float f, unsigned short &hi, unsigned short &lo){
    union { float f; unsigned u; } v; v.f = f;
    const unsigned uh = v.u & 0xFFFF0000u;
    hi = (unsigned short)(uh >> 16);
    union { unsigned u; float f; } w; w.u = uh;
    union { float f; unsigned u; } r; r.f = f - w.f;
    lo = (unsigned short)(r.u >> 16);
}
static __device__ __forceinline__ float sigf(float v){
    return __builtin_amdgcn_rcpf(1.0f + __builtin_amdgcn_exp2f(-1.4426950408889634f * v));
}
static __device__ __forceinline__ float tanhf2(float v){
    return 2.0f * __builtin_amdgcn_rcpf(1.0f + __builtin_amdgcn_exp2f(-2.8853900817779268f * v)) - 1.0f;
}
static __device__ __forceinline__ frag_ab loadBfrag(const float* __restrict__ W, int ldk, int jcol, int k0){
    const float* p = W + jcol * ldk + k0;
    frag_ab r;
    #pragma unroll
    for (int i = 0; i < 8; ++i) r[i] = (short)f2bf_rnd(p[i]);
    return r;
}
static __device__ __forceinline__ float sel4(frag_cd a, int q){
    const float v01 = (q == 0) ? a[0] : a[1];
    const float v23 = (q == 2) ? a[2] : a[3];
    return (q < 2) ? v01 : v23;
}
static __device__ __forceinline__ frag_cd splat4(float v){ return frag_cd{v,v,v,v}; }

#define MFMA(a,b,c) __builtin_amdgcn_mfma_f32_16x16x32_bf16((a),(b),(c),0,0,0)

// R7: same dataflow as R6 (4 batches/block, 512 blocks, 2 blocks/CU, depth-2/3
// LDS rings, 1 barrier/step) with the issue-work cut:
//  - t-loop unrolled x6 (LCM of ring periods) -> all ring slots are literals,
//    LDS addresses fold to base+imm (kills per-step address VALU).
//  - L2 dedup: waves 0,1 each compute L2 for their 16-col half x ALL 4 batches
//    (waves 2,3 did bit-identical MFMAs in R6); batch=lq per lane via sel4;
//    all-lane unique-address H2 writes (no exec mask). -36 MFMA/block/step.
//  - waves 2,3 own x staging (float2/thread, cross-phase register hold).
__global__ __launch_bounds__(256, 2)
void gru_fused6(const float* __restrict__ x,
                const float* __restrict__ Wih1, const float* __restrict__ Whh1,
                const float* __restrict__ bih1, const float* __restrict__ bhh1,
                const float* __restrict__ Wih2, const float* __restrict__ Whh2,
                const float* __restrict__ bih2, const float* __restrict__ bhh2,
                const float* __restrict__ Wfc,  const float* __restrict__ bfc,
                const float* __restrict__ Wout, const float* __restrict__ bout,
                float* __restrict__ out)
{
    __shared__ __align__(16) unsigned short RGhi[2][288], RGlo[2][288];  // h1 ring [slot][b*72+col]
    __shared__ __align__(16) unsigned short XHI[3][288],  XLO[3][288];   // x ring (depth 3)
    __shared__ __align__(16) unsigned short H2HI[2][160], H2LO[2][160];  // h2 ring [slot][b*40+j]
    __shared__ float HFIN[128];
    __shared__ float FCS[64];

    const int tid  = threadIdx.x;
    const int wv   = tid >> 6;
    const int lane = tid & 63;
    const int lrow = lane & 15;
    const int lq   = lane >> 4;
    const int r4   = lrow & 3;
    const int bbase = blockIdx.x * 4;
    const bool l2w = (wv < 2);
    const bool xw  = (wv >= 2);

    for (int i = tid; i < 288; i += 256){ RGhi[1][i] = 0; RGlo[1][i] = 0; }
    for (int i = tid; i < 160; i += 256){ H2HI[1][i] = 0; H2LO[1][i] = 0; }

    // prologue x staging: x(0)->slot0, x(1)->slot1
    {
        const int xb = tid >> 6, xk = tid & 63;
        #pragma unroll
        for (int s = 0; s < 2; ++s){
            unsigned short hb, lb;
            tsplit(x[((size_t)(bbase + xb) * T_SEQ + s) * 64 + xk], hb, lb);
            XHI[s][xb*72 + xk] = hb; XLO[s][xb*72 + xk] = lb;
        }
    }

    // ---- L1 weights/biases (all waves) ----
    const int col1 = wv*16 + lrow;
    frag_ab Wr1i[2], Wz1i[2], Wn1i[2], Wr1h[2], Wz1h[2], Wn1h[2];
    #pragma unroll
    for (int kf = 0; kf < 2; ++kf){
        const int k0 = kf*32 + 8*lq;
        Wr1i[kf] = loadBfrag(Wih1, 64, col1,       k0);
        Wz1i[kf] = loadBfrag(Wih1, 64, 64  + col1, k0);
        Wn1i[kf] = loadBfrag(Wih1, 64, 128 + col1, k0);
        Wr1h[kf] = loadBfrag(Whh1, 64, col1,       k0);
        Wz1h[kf] = loadBfrag(Whh1, 64, 64  + col1, k0);
        Wn1h[kf] = loadBfrag(Whh1, 64, 128 + col1, k0);
    }
    const frag_cd BR1 = splat4(bih1[col1] + bhh1[col1]);
    const frag_cd BZ1 = splat4(bih1[64 + col1] + bhh1[64 + col1]);
    const frag_cd BI1 = splat4(bih1[128 + col1]);
    const frag_cd BH1 = splat4(bhh1[128 + col1]);

    // ---- L2 weights/biases (waves 0,1 only) ----
    const int c2 = (wv & 1)*16 + lrow;
    frag_ab Wr2i[2], Wz2i[2], Wn2i[2], Wr2h, Wz2h, Wn2h;
    frag_cd BR2 = splat4(0.f), BZ2 = splat4(0.f), BI2 = splat4(0.f), BH2 = splat4(0.f);
    if (l2w){
        #pragma unroll
        for (int kf = 0; kf < 2; ++kf){
            const int k0 = kf*32 + 8*lq;
            Wr2i[kf] = loadBfrag(Wih2, 64, c2,      k0);
            Wz2i[kf] = loadBfrag(Wih2, 64, 32 + c2, k0);
            Wn2i[kf] = loadBfrag(Wih2, 64, 64 + c2, k0);
        }
        Wr2h = loadBfrag(Whh2, 32, c2,      8*lq);
        Wz2h = loadBfrag(Whh2, 32, 32 + c2, 8*lq);
        Wn2h = loadBfrag(Whh2, 32, 64 + c2, 8*lq);
        BR2 = splat4(bih2[c2] + bhh2[c2]);
        BZ2 = splat4(bih2[32 + c2] + bhh2[32 + c2]);
        BI2 = splat4(bih2[64 + c2]);
        BH2 = splat4(bhh2[64 + c2]);
    }

    // x staging ownership (waves 2,3): 2 elems (float2) per thread
    const int u   = tid & 127;
    const int xb2 = u >> 5, xk2 = (u & 31)*2;
    const float* xld = x + ((size_t)(bbase + xb2) * T_SEQ + 3)*64 + xk2;
    float2 xpend2 = {0.f, 0.f};
    if (xw) xpend2 = *(const float2*)(x + ((size_t)(bbase + xb2) * T_SEQ + 2)*64 + xk2);

    // loop-invariant offsets
    const int fo0 = r4*72 + 8*lq;     // + kf*32
    const int go2 = r4*40 + 8*lq;
    const int rgo = lq*72 + col1;
    const int h2o = lq*40 + c2;
    const int xo2 = xb2*72 + xk2;

    float hs1 = 0.f;   // L1 state: batch lq, col col1
    float hs2 = 0.f;   // L2 state (waves 0,1): batch lq, col c2

    __syncthreads();

#define GSTEP(SRR, SCC, DO_L1, DO_L2, DO_X, XCLAMP, TT) do{                   \
    const int SPP = (SCC)^1; const int SWW = ((SRR)+2)%3;                     \
    float2 xn2 = {0.f, 0.f};                                                  \
    if ((DO_X) && xw){                                                        \
        xn2 = *(const float2*)xld;                                            \
        if (!(XCLAMP) || ((TT) <= 507)) xld += 64;                            \
        unsigned short a0,b0,a1,b1;                                           \
        tsplit(xpend2.x, a0, b0); tsplit(xpend2.y, a1, b1);                   \
        *(unsigned*)(&XHI[SWW][xo2]) = (unsigned)a0 | ((unsigned)a1 << 16);   \
        *(unsigned*)(&XLO[SWW][xo2]) = (unsigned)b0 | ((unsigned)b1 << 16);   \
    }                                                                         \
    frag_ab hhf0, hhf1, hlf0, hlf1;                                           \
    hhf0 = *(const frag_ab*)(&RGhi[SPP][fo0]);                                \
    hhf1 = *(const frag_ab*)(&RGhi[SPP][fo0 + 32]);                           \
    hlf0 = *(const frag_ab*)(&RGlo[SPP][fo0]);                                \
    hlf1 = *(const frag_ab*)(&RGlo[SPP][fo0 + 32]);                           \
    if (DO_L1){                                                               \
        frag_ab xhf0, xhf1, xlf0, xlf1;                                       \
        xhf0 = *(const frag_ab*)(&XHI[SRR][fo0]);                             \
        xhf1 = *(const frag_ab*)(&XHI[SRR][fo0 + 32]);                        \
        xlf0 = *(const frag_ab*)(&XLO[SRR][fo0]);                             \
        xlf1 = *(const frag_ab*)(&XLO[SRR][fo0 + 32]);                        \
        frag_cd A0 = BR1, A1 = BZ1, A2 = BI1, A3 = BH1;                       \
        A0 = MFMA(xhf0, Wr1i[0], A0); A0 = MFMA(xlf0, Wr1i[0], A0);           \
        A0 = MFMA(hhf0, Wr1h[0], A0); A0 = MFMA(hlf0, Wr1h[0], A0);           \
        A0 = MFMA(xhf1, Wr1i[1], A0); A0 = MFMA(xlf1, Wr1i[1], A0);           \
        A0 = MFMA(hhf1, Wr1h[1], A0); A0 = MFMA(hlf1, Wr1h[1], A0);           \
        A1 = MFMA(xhf0, Wz1i[0], A1); A1 = MFMA(xlf0, Wz1i[0], A1);           \
        A1 = MFMA(hhf0, Wz1h[0], A1); A1 = MFMA(hlf0, Wz1h[0], A1);           \
        A1 = MFMA(xhf1, Wz1i[1], A1); A1 = MFMA(xlf1, Wz1i[1], A1);           \
        A1 = MFMA(hhf1, Wz1h[1], A1); A1 = MFMA(hlf1, Wz1h[1], A1);           \
        A2 = MFMA(xhf0, Wn1i[0], A2); A2 = MFMA(xlf0, Wn1i[0], A2);           \
        A2 = MFMA(xhf1, Wn1i[1], A2); A2 = MFMA(xlf1, Wn1i[1], A2);           \
        A3 = MFMA(hhf0, Wn1h[0], A3); A3 = MFMA(hlf0, Wn1h[0], A3);           \
        A3 = MFMA(hhf1, Wn1h[1], A3); A3 = MFMA(hlf1, Wn1h[1], A3);           \
        const float vR = sel4(A0, lq), vZ = sel4(A1, lq);                     \
        const float vI = sel4(A2, lq), vH = sel4(A3, lq);                     \
        const float rg = sigf(vR), zg = sigf(vZ);                             \
        const float ng = tanhf2(vI + rg*vH);                                  \
        hs1 = ng + zg*(hs1 - ng);                                             \
        unsigned short hb, lb; tsplit(hs1, hb, lb);                           \
        RGhi[SCC][rgo] = hb; RGlo[SCC][rgo] = lb;                             \
    }                                                                         \
    if ((DO_L2) && l2w){                                                      \
        frag_ab g2hf, g2lf;                                                   \
        g2hf = *(const frag_ab*)(&H2HI[SCC][go2]);                            \
        g2lf = *(const frag_ab*)(&H2LO[SCC][go2]);                            \
        frag_cd B0 = BR2, B1 = BZ2, B2 = BI2, B3 = BH2;                       \
        B0 = MFMA(hhf0, Wr2i[0], B0); B0 = MFMA(hlf0, Wr2i[0], B0);           \
        B0 = MFMA(hhf1, Wr2i[1], B0); B0 = MFMA(hlf1, Wr2i[1], B0);           \
        B1 = MFMA(hhf0, Wz2i[0], B1); B1 = MFMA(hlf0, Wz2i[0], B1);           \
        B1 = MFMA(hhf1, Wz2i[1], B1); B1 = MFMA(hlf1, Wz2i[1], B1);           \
        B2 = MFMA(hhf0, Wn2i[0], B2); B2 = MFMA(hlf0, Wn2i[0], B2);           \
        B2 = MFMA(hhf1, Wn2i[1], B2); B2 = MFMA(hlf1, Wn2i[1], B2);           \
        B0 = MFMA(g2hf, Wr2h, B0); B0 = MFMA(g2lf, Wr2h, B0);                 \
        B1 = MFMA(g2hf, Wz2h, B1); B1 = MFMA(g2lf, Wz2h, B1);                 \
        B3 = MFMA(g2hf, Wn2h, B3); B3 = MFMA(g2lf, Wn2h, B3);                 \
        const float wR = sel4(B0, lq), wZ = sel4(B1, lq);                     \
        const float wI = sel4(B2, lq), wH = sel4(B3, lq);                     \
        const float rv = sigf(wR), zv = sigf(wZ);                             \
        const float nv = tanhf2(wI + rv*wH);                                  \
        hs2 = nv + zv*(hs2 - nv);                                             \
        unsigned short hb, lb; tsplit(hs2, hb, lb);                           \
        H2HI[SPP][h2o] = hb; H2LO[SPP][h2o] = lb;                             \
    }                                                                         \
    if ((DO_X) && xw){ xpend2 = xn2; }                                        \
    __syncthreads();                                                          \
}while(0)

    // phase 0
    GSTEP(0, 0, true, false, true, false, 0);

    // phases 1..498: 83 iterations x 6 (ring slots literal per position)
    #pragma unroll 1
    for (int i = 0; i < 83; ++i){
        GSTEP(1, 1, true, true, true, false, 0);
        GSTEP(2, 0, true, true, true, false, 0);
        GSTEP(0, 1, true, true, true, false, 0);
        GSTEP(1, 0, true, true, true, false, 0);
        GSTEP(2, 1, true, true, true, false, 0);
        GSTEP(0, 0, true, true, true, false, 0);
    }

    // phases 499..512: generic tail (runtime slots, x-clamp)
    {
        int sr = 1, sc = 1;
        #pragma unroll 1
        for (int t = 499; t <= T_SEQ; ++t){
            const bool dl1 = (t < T_SEQ);
            GSTEP(sr, sc, dl1, true, dl1, true, t);
            sr = (sr == 2) ? 0 : sr + 1;
            sc ^= 1;
        }
    }
#undef GSTEP

    // head: h2(511) is in H2 slot 1
    if (tid < 128){
        const int r = tid >> 5, c = tid & 31;
        HFIN[r*32 + c] = bf2f(H2HI[1][r*40 + c]) + bf2f(H2LO[1][r*40 + c]);
    }
    __syncthreads();
    if (tid < 64){
        const int b = tid >> 4, f = tid & 15;
        float s = bfc[f];
        #pragma unroll
        for (int k = 0; k < 32; ++k) s += HFIN[b*32 + k] * Wfc[f*32 + k];
        FCS[b*16 + f] = fmaxf(s, 0.f);
    }
    __syncthreads();
    if (tid < 4){
        float o = bout[0];
        #pragma unroll
        for (int f = 0; f < 16; ++f) o += FCS[tid*16 + f] * Wout[f];
        out[bbase + tid] = o;
    }
}

extern "C" void kernel_launch(void* const* d_in, const int* in_sizes, int n_in,
                              void* d_out, int out_size, void* d_ws, size_t ws_size,
                              hipStream_t stream) {
    const float* x    = (const float*)d_in[0];
    const float* Wih1 = (const float*)d_in[1];
    const float* Whh1 = (const float*)d_in[2];
    const float* bih1 = (const float*)d_in[3];
    const float* bhh1 = (const float*)d_in[4];
    const float* Wih2 = (const float*)d_in[5];
    const float* Whh2 = (const float*)d_in[6];
    const float* bih2 = (const float*)d_in[7];
    const float* bhh2 = (const float*)d_in[8];
    const float* Wfc  = (const float*)d_in[9];
    const float* bfc  = (const float*)d_in[10];
    const float* Wout = (const float*)d_in[11];
    const float* bout = (const float*)d_in[12];

    gru_fused6<<<512, 256, 0, stream>>>(x, Wih1, Whh1, bih1, bhh1,
                                        Wih2, Whh2, bih2, bhh2,
                                        Wfc, bfc, Wout, bout, (float*)d_out);
}

// Round 8
// 389.587 us; speedup vs baseline: 3.0421x; 1.1638x over previous
//
#include <hip/hip_runtime.h>
#include <hip/hip_bf16.h>

#define T_SEQ 512

typedef __attribute__((ext_vector_type(8))) short frag_ab;
typedef __attribute__((ext_vector_type(4))) float frag_cd;

static __device__ __forceinline__ unsigned short f2bf_rnd(float f){
    union { float f; unsigned u; } v; v.f = f;
    unsigned r = v.u + 0x7fffu + ((v.u >> 16) & 1u);
    return (unsigned short)(r >> 16);
}
static __device__ __forceinline__ float bf2f(unsigned short h){
    union { unsigned u; float f; } v; v.u = ((unsigned)h) << 16;
    return v.f;
}
static __device__ __forceinline__ void tsplit(float f, unsigned short &hi, unsigned short &lo){
    union { float f; unsigned u; } v; v.f = f;
    const unsigned uh = v.u & 0xFFFF0000u;
    hi = (unsigned short)(uh >> 16);
    union { unsigned u; float f; } w; w.u = uh;
    union { float f; unsigned u; } r; r.f = f - w.f;
    lo = (unsigned short)(r.u >> 16);
}
static __device__ __forceinline__ float sigf(float v){
    return __builtin_amdgcn_rcpf(1.0f + __builtin_amdgcn_exp2f(-1.4426950408889634f * v));
}
static __device__ __forceinline__ float tanhf2(float v){
    return 2.0f * __builtin_amdgcn_rcpf(1.0f + __builtin_amdgcn_exp2f(-2.8853900817779268f * v)) - 1.0f;
}
static __device__ __forceinline__ frag_ab loadBfrag(const float* __restrict__ W, int ldk, int jcol, int k0){
    const float* p = W + jcol * ldk + k0;
    frag_ab r;
    #pragma unroll
    for (int i = 0; i < 8; ++i) r[i] = (short)f2bf_rnd(p[i]);
    return r;
}
static __device__ __forceinline__ float sel4(frag_cd a, int q){
    const float v01 = (q == 0) ? a[0] : a[1];
    const float v23 = (q == 2) ? a[2] : a[3];
    return (q < 2) ? v01 : v23;
}
static __device__ __forceinline__ frag_cd splat4(float v){ return frag_cd{v,v,v,v}; }

#define MFMA(a,b,c) __builtin_amdgcn_mfma_f32_16x16x32_bf16((a),(b),(c),0,0,0)

// Counted barrier: LDS visibility only (lgkmcnt 0), vmcnt NOT drained --
// in-flight x global loads survive the barrier (T4); their wait happens at
// the register use one phase later.  __syncthreads would drain vmcnt(0) and
// pin the step period to HBM latency (R7's ~2100cy/step plateau).
#define BAR() asm volatile("s_waitcnt lgkmcnt(0)\ns_barrier" ::: "memory")

// R8 = R7 + counted-vmcnt barrier + x-lo drop (x staged as single rnd-bf16;
// XLO ring deleted; L1 24->18 MFMA/wave) + depth-4 x ring with 2-phase
// register hold + block-parity swap of (L2 wave pair | staging wave pair).
__global__ __launch_bounds__(256, 2)
void gru_fused7(const float* __restrict__ x,
                const float* __restrict__ Wih1, const float* __restrict__ Whh1,
                const float* __restrict__ bih1, const float* __restrict__ bhh1,
                const float* __restrict__ Wih2, const float* __restrict__ Whh2,
                const float* __restrict__ bih2, const float* __restrict__ bhh2,
                const float* __restrict__ Wfc,  const float* __restrict__ bfc,
                const float* __restrict__ Wout, const float* __restrict__ bout,
                float* __restrict__ out)
{
    __shared__ __align__(16) unsigned short RGhi[2][288], RGlo[2][288];  // h1 ring [slot][b*72+col]
    __shared__ __align__(16) unsigned short XHI[4][288];                 // x ring, depth 4, hi only
    __shared__ __align__(16) unsigned short H2HI[2][160], H2LO[2][160];  // h2 ring [slot][b*40+j]
    __shared__ float HFIN[128];
    __shared__ float FCS[64];

    const int tid  = threadIdx.x;
    const int wv   = tid >> 6;
    const int lane = tid & 63;
    const int lrow = lane & 15;
    const int lq   = lane >> 4;
    const int r4   = lrow & 3;
    const int bbase = blockIdx.x * 4;
    const int hv   = (int)(blockIdx.x & 1);      // parity: which wave-pair is heavy
    const bool l2w = ((wv >> 1) == hv);          // L2 wave pair
    const bool xw  = !l2w;                       // x-staging wave pair

    for (int i = tid; i < 288; i += 256){ RGhi[1][i] = 0; RGlo[1][i] = 0; }
    for (int i = tid; i < 160; i += 256){ H2HI[1][i] = 0; H2LO[1][i] = 0; }

    // prologue x staging: x(0)->slot0, x(1)->slot1 (rnd-bf16, hi only)
    {
        const int b = tid >> 6, k = tid & 63;
        #pragma unroll
        for (int s = 0; s < 2; ++s)
            XHI[s][b*72 + k] = f2bf_rnd(x[((size_t)(bbase + b) * T_SEQ + s) * 64 + k]);
    }

    // ---- L1 weights/biases (all waves) ----
    const int col1 = wv*16 + lrow;
    frag_ab Wr1i[2], Wz1i[2], Wn1i[2], Wr1h[2], Wz1h[2], Wn1h[2];
    #pragma unroll
    for (int kf = 0; kf < 2; ++kf){
        const int k0 = kf*32 + 8*lq;
        Wr1i[kf] = loadBfrag(Wih1, 64, col1,       k0);
        Wz1i[kf] = loadBfrag(Wih1, 64, 64  + col1, k0);
        Wn1i[kf] = loadBfrag(Wih1, 64, 128 + col1, k0);
        Wr1h[kf] = loadBfrag(Whh1, 64, col1,       k0);
        Wz1h[kf] = loadBfrag(Whh1, 64, 64  + col1, k0);
        Wn1h[kf] = loadBfrag(Whh1, 64, 128 + col1, k0);
    }
    const frag_cd BR1 = splat4(bih1[col1] + bhh1[col1]);
    const frag_cd BZ1 = splat4(bih1[64 + col1] + bhh1[64 + col1]);
    const frag_cd BI1 = splat4(bih1[128 + col1]);
    const frag_cd BH1 = splat4(bhh1[128 + col1]);

    // ---- L2 weights/biases (heavy pair only) ----
    const int c2 = (wv & 1)*16 + lrow;
    frag_ab Wr2i[2], Wz2i[2], Wn2i[2], Wr2h, Wz2h, Wn2h;
    frag_cd BR2 = splat4(0.f), BZ2 = splat4(0.f), BI2 = splat4(0.f), BH2 = splat4(0.f);
    if (l2w){
        #pragma unroll
        for (int kf = 0; kf < 2; ++kf){
            const int k0 = kf*32 + 8*lq;
            Wr2i[kf] = loadBfrag(Wih2, 64, c2,      k0);
            Wz2i[kf] = loadBfrag(Wih2, 64, 32 + c2, k0);
            Wn2i[kf] = loadBfrag(Wih2, 64, 64 + c2, k0);
        }
        Wr2h = loadBfrag(Whh2, 32, c2,      8*lq);
        Wz2h = loadBfrag(Whh2, 32, 32 + c2, 8*lq);
        Wn2h = loadBfrag(Whh2, 32, 64 + c2, 8*lq);
        BR2 = splat4(bih2[c2] + bhh2[c2]);
        BZ2 = splat4(bih2[32 + c2] + bhh2[32 + c2]);
        BI2 = splat4(bih2[64 + c2]);
        BH2 = splat4(bhh2[64 + c2]);
    }

    // x staging (staging pair): 2 floats/thread; 2-phase register hold
    const int u   = tid & 127;
    const int xb2 = u >> 5, xk2 = (u & 31)*2;
    const int xo2 = xb2*72 + xk2;
    const float* xld = x + ((size_t)(bbase + xb2) * T_SEQ + 4)*64 + xk2;
    float2 xp0 = {0.f,0.f}, xp1 = {0.f,0.f};
    if (xw){
        xp0 = *(const float2*)(x + ((size_t)(bbase + xb2) * T_SEQ + 2)*64 + xk2);
        xp1 = *(const float2*)(x + ((size_t)(bbase + xb2) * T_SEQ + 3)*64 + xk2);
    }

    const int fo0 = r4*72 + 8*lq;
    const int go2 = r4*40 + 8*lq;
    const int rgo = lq*72 + col1;
    const int h2o = lq*40 + c2;

    float hs1 = 0.f;   // L1 state: batch lq, col col1
    float hs2 = 0.f;   // L2 state (heavy pair): batch lq, col c2

    __syncthreads();   // once; full drain harmless here

// SX = t&3 (x read slot; write slot = SX^2), SP = t&1 (RG write / H2 read slot)
#define GSTEP(SX, SP, DO_L1, DO_L2, DO_X, DO_XLD) do{                         \
    if ((DO_X) && xw){                                                        \
        float2 xn2;                                                           \
        if (DO_XLD){ xn2 = *(const float2*)xld; xld += 64; }                  \
        const unsigned short a0 = f2bf_rnd(xp0.x), a1 = f2bf_rnd(xp0.y);      \
        *(unsigned*)(&XHI[(SX)^2][xo2]) = (unsigned)a0 | ((unsigned)a1 << 16);\
        xp0 = xp1;                                                            \
        if (DO_XLD) xp1 = xn2;                                                \
    }                                                                         \
    frag_ab hhf0, hhf1, hlf0, hlf1;                                           \
    hhf0 = *(const frag_ab*)(&RGhi[(SP)^1][fo0]);                             \
    hhf1 = *(const frag_ab*)(&RGhi[(SP)^1][fo0 + 32]);                        \
    hlf0 = *(const frag_ab*)(&RGlo[(SP)^1][fo0]);                             \
    hlf1 = *(const frag_ab*)(&RGlo[(SP)^1][fo0 + 32]);                        \
    if (DO_L1){                                                               \
        frag_ab xhf0, xhf1;                                                   \
        xhf0 = *(const frag_ab*)(&XHI[SX][fo0]);                              \
        xhf1 = *(const frag_ab*)(&XHI[SX][fo0 + 32]);                         \
        frag_cd A0 = BR1, A1 = BZ1, A2 = BI1, A3 = BH1;                       \
        A0 = MFMA(xhf0, Wr1i[0], A0); A0 = MFMA(xhf1, Wr1i[1], A0);           \
        A0 = MFMA(hhf0, Wr1h[0], A0); A0 = MFMA(hlf0, Wr1h[0], A0);           \
        A0 = MFMA(hhf1, Wr1h[1], A0); A0 = MFMA(hlf1, Wr1h[1], A0);           \
        A1 = MFMA(xhf0, Wz1i[0], A1); A1 = MFMA(xhf1, Wz1i[1], A1);           \
        A1 = MFMA(hhf0, Wz1h[0], A1); A1 = MFMA(hlf0, Wz1h[0], A1);           \
        A1 = MFMA(hhf1, Wz1h[1], A1); A1 = MFMA(hlf1, Wz1h[1], A1);           \
        A2 = MFMA(xhf0, Wn1i[0], A2); A2 = MFMA(xhf1, Wn1i[1], A2);           \
        A3 = MFMA(hhf0, Wn1h[0], A3); A3 = MFMA(hlf0, Wn1h[0], A3);           \
        A3 = MFMA(hhf1, Wn1h[1], A3); A3 = MFMA(hlf1, Wn1h[1], A3);           \
        const float vR = sel4(A0, lq), vZ = sel4(A1, lq);                     \
        const float vI = sel4(A2, lq), vH = sel4(A3, lq);                     \
        const float rg = sigf(vR), zg = sigf(vZ);                             \
        const float ng = tanhf2(vI + rg*vH);                                  \
        hs1 = ng + zg*(hs1 - ng);                                             \
        unsigned short hb, lb; tsplit(hs1, hb, lb);                           \
        RGhi[SP][rgo] = hb; RGlo[SP][rgo] = lb;                               \
    }                                                                         \
    if ((DO_L2) && l2w){                                                      \
        frag_ab g2hf, g2lf;                                                   \
        g2hf = *(const frag_ab*)(&H2HI[SP][go2]);                             \
        g2lf = *(const frag_ab*)(&H2LO[SP][go2]);                             \
        frag_cd B0 = BR2, B1 = BZ2, B2 = BI2, B3 = BH2;                       \
        B0 = MFMA(hhf0, Wr2i[0], B0); B0 = MFMA(hlf0, Wr2i[0], B0);           \
        B0 = MFMA(hhf1, Wr2i[1], B0); B0 = MFMA(hlf1, Wr2i[1], B0);           \
        B1 = MFMA(hhf0, Wz2i[0], B1); B1 = MFMA(hlf0, Wz2i[0], B1);           \
        B1 = MFMA(hhf1, Wz2i[1], B1); B1 = MFMA(hlf1, Wz2i[1], B1);           \
        B2 = MFMA(hhf0, Wn2i[0], B2); B2 = MFMA(hlf0, Wn2i[0], B2);           \
        B2 = MFMA(hhf1, Wn2i[1], B2); B2 = MFMA(hlf1, Wn2i[1], B2);           \
        B0 = MFMA(g2hf, Wr2h, B0); B0 = MFMA(g2lf, Wr2h, B0);                 \
        B1 = MFMA(g2hf, Wz2h, B1); B1 = MFMA(g2lf, Wz2h, B1);                 \
        B3 = MFMA(g2hf, Wn2h, B3); B3 = MFMA(g2lf, Wn2h, B3);                 \
        const float wR = sel4(B0, lq), wZ = sel4(B1, lq);                     \
        const float wI = sel4(B2, lq), wH = sel4(B3, lq);                     \
        const float rv = sigf(wR), zv = sigf(wZ);                             \
        const float nv = tanhf2(wI + rv*wH);                                  \
        hs2 = nv + zv*(hs2 - nv);                                             \
        unsigned short hb, lb; tsplit(hs2, hb, lb);                           \
        H2HI[(SP)^1][h2o] = hb; H2LO[(SP)^1][h2o] = lb;                       \
    }                                                                         \
    BAR();                                                                    \
}while(0)

    // phase 0 (L1 + staging; no L2 yet)
    GSTEP(0, 0, true, false, true, true);

    // phases 1..504: 126 iterations x 4 (all ring slots literal)
    #pragma unroll 1
    for (int i = 0; i < 126; ++i){
        GSTEP(1, 1, true, true, true, true);
        GSTEP(2, 0, true, true, true, true);
        GSTEP(3, 1, true, true, true, true);
        GSTEP(0, 0, true, true, true, true);
    }

    // tail phases 505..512 (literal slots; load-clamp by flag)
    GSTEP(1, 1, true, true, true,  true);    // 505: loads row 509
    GSTEP(2, 0, true, true, true,  true);    // 506: loads row 510
    GSTEP(3, 1, true, true, true,  true);    // 507: loads row 511
    GSTEP(0, 0, true, true, true,  false);   // 508: write x(510)
    GSTEP(1, 1, true, true, true,  false);   // 509: write x(511)
    GSTEP(2, 0, true, true, false, false);   // 510
    GSTEP(3, 1, true, true, false, false);   // 511
    GSTEP(0, 0, false, true, false, false);  // 512: L2 final step
#undef GSTEP

    // head: h2(511) in H2 slot 1
    if (tid < 128){
        const int r = tid >> 5, c = tid & 31;
        HFIN[r*32 + c] = bf2f(H2HI[1][r*40 + c]) + bf2f(H2LO[1][r*40 + c]);
    }
    __syncthreads();
    if (tid < 64){
        const int b = tid >> 4, f = tid & 15;
        float s = bfc[f];
        #pragma unroll
        for (int k = 0; k < 32; ++k) s += HFIN[b*32 + k] * Wfc[f*32 + k];
        FCS[b*16 + f] = fmaxf(s, 0.f);
    }
    __syncthreads();
    if (tid < 4){
        float o = bout[0];
        #pragma unroll
        for (int f = 0; f < 16; ++f) o += FCS[tid*16 + f] * Wout[f];
        out[bbase + tid] = o;
    }
}

extern "C" void kernel_launch(void* const* d_in, const int* in_sizes, int n_in,
                              void* d_out, int out_size, void* d_ws, size_t ws_size,
                              hipStream_t stream) {
    const float* x    = (const float*)d_in[0];
    const float* Wih1 = (const float*)d_in[1];
    const float* Whh1 = (const float*)d_in[2];
    const float* bih1 = (const float*)d_in[3];
    const float* bhh1 = (const float*)d_in[4];
    const float* Wih2 = (const float*)d_in[5];
    const float* Whh2 = (const float*)d_in[6];
    const float* bih2 = (const float*)d_in[7];
    const float* bhh2 = (const float*)d_in[8];
    const float* Wfc  = (const float*)d_in[9];
    const float* bfc  = (const float*)d_in[10];
    const float* Wout = (const float*)d_in[11];
    const float* bout = (const float*)d_in[12];

    gru_fused7<<<512, 256, 0, stream>>>(x, Wih1, Whh1, bih1, bhh1,
                                        Wih2, Whh2, bih2, bhh2,
                                        Wfc, bfc, Wout, bout, (float*)d_out);
}

// Round 9
// 322.624 us; speedup vs baseline: 3.6735x; 1.2076x over previous
//
#include <hip/hip_runtime.h>
#include <hip/hip_bf16.h>

#define T_SEQ 512

typedef __attribute__((ext_vector_type(8))) short frag_ab;
typedef __attribute__((ext_vector_type(4))) float frag_cd;

static __device__ __forceinline__ unsigned short f2bf_rnd(float f){
    union { float f; unsigned u; } v; v.f = f;
    unsigned r = v.u + 0x7fffu + ((v.u >> 16) & 1u);
    return (unsigned short)(r >> 16);
}
static __device__ __forceinline__ float bf2f(unsigned short h){
    union { unsigned u; float f; } v; v.u = ((unsigned)h) << 16;
    return v.f;
}
static __device__ __forceinline__ void tsplit(float f, unsigned short &hi, unsigned short &lo){
    union { float f; unsigned u; } v; v.f = f;
    const unsigned uh = v.u & 0xFFFF0000u;
    hi = (unsigned short)(uh >> 16);
    union { unsigned u; float f; } w; w.u = uh;
    union { float f; unsigned u; } r; r.f = f - w.f;
    lo = (unsigned short)(r.u >> 16);
}
static __device__ __forceinline__ float sigf(float v){
    return __builtin_amdgcn_rcpf(1.0f + __builtin_amdgcn_exp2f(-1.4426950408889634f * v));
}
static __device__ __forceinline__ float tanhf2(float v){
    return 2.0f * __builtin_amdgcn_rcpf(1.0f + __builtin_amdgcn_exp2f(-2.8853900817779268f * v)) - 1.0f;
}
static __device__ __forceinline__ frag_ab loadBfrag(const float* __restrict__ W, int ldk, int jcol, int k0){
    const float* p = W + jcol * ldk + k0;
    frag_ab r;
    #pragma unroll
    for (int i = 0; i < 8; ++i) r[i] = (short)f2bf_rnd(p[i]);
    return r;
}
static __device__ __forceinline__ float sel4(frag_cd a, int q){
    const float v01 = (q == 0) ? a[0] : a[1];
    const float v23 = (q == 2) ? a[2] : a[3];
    return (q < 2) ? v01 : v23;
}
static __device__ __forceinline__ frag_cd splat4(float v){ return frag_cd{v,v,v,v}; }

#define MFMA(a,b,c) __builtin_amdgcn_mfma_f32_16x16x32_bf16((a),(b),(c),0,0,0)

// Counted barrier: drain LDS only; in-flight global x loads cross the barrier.
#define BAR() asm volatile("s_waitcnt lgkmcnt(0)\ns_barrier" ::: "memory")

// R9: 512-thread blocks (8 waves), batch 4, 512 blocks -> 2 blocks/CU =
// 4 waves/SIMD. One role per wave (short critical path per wave):
//   wv0-3: L1 for 16 cols each (18 MFMA + 1 gate chain)
//   wv4-7: by block parity, one pair = L2 (12 MFMA: ih2 h1-hi only + hh2
//          hi/lo), other pair = x staging. Parity swap -> every SIMD hosts
//          2xL1 + 1xL2 + 1xstaging across the two co-resident blocks.
// Rings as R8 (x: depth-4 hi-only; h1: depth-2 hi/lo; h2: depth-2 hi/lo).
__global__ __launch_bounds__(512, 2)
void gru_fused8(const float* __restrict__ x,
                const float* __restrict__ Wih1, const float* __restrict__ Whh1,
                const float* __restrict__ bih1, const float* __restrict__ bhh1,
                const float* __restrict__ Wih2, const float* __restrict__ Whh2,
                const float* __restrict__ bih2, const float* __restrict__ bhh2,
                const float* __restrict__ Wfc,  const float* __restrict__ bfc,
                const float* __restrict__ Wout, const float* __restrict__ bout,
                float* __restrict__ out)
{
    __shared__ __align__(16) unsigned short RGhi[2][288], RGlo[2][288];
    __shared__ __align__(16) unsigned short XHI[4][288];
    __shared__ __align__(16) unsigned short H2HI[2][160], H2LO[2][160];
    __shared__ float HFIN[128];
    __shared__ float FCS[64];

    const int tid  = threadIdx.x;
    const int wv   = tid >> 6;
    const int lane = tid & 63;
    const int lrow = lane & 15;
    const int lq   = lane >> 4;
    const int r4   = lrow & 3;
    const int bbase = blockIdx.x * 4;
    const int hv   = (int)(blockIdx.x & 1);
    const bool isL1 = (wv < 4);
    const bool isL2 = (!isL1) && (((wv >> 1) & 1) == hv);
    const bool isXW = (!isL1) && !isL2;

    for (int i = tid; i < 288; i += 512){ RGhi[1][i] = 0; RGlo[1][i] = 0; }
    for (int i = tid; i < 160; i += 512){ H2HI[1][i] = 0; H2LO[1][i] = 0; }

    // prologue x staging: x(0)->slot0, x(1)->slot1 (512 thr x 1 elem)
    {
        const int s = tid >> 8, idx = tid & 255;
        const int b = idx >> 6, k = idx & 63;
        XHI[s][b*72 + k] = f2bf_rnd(x[((size_t)(bbase + b) * T_SEQ + s) * 64 + k]);
    }

    // role-unioned persistent registers
    frag_ab WF[12];
    frag_cd BF[4];

    if (isL1){
        const int col1 = wv*16 + lrow;
        #pragma unroll
        for (int kf = 0; kf < 2; ++kf){
            const int k0 = kf*32 + 8*lq;
            WF[0+kf]  = loadBfrag(Wih1, 64, col1,       k0);
            WF[2+kf]  = loadBfrag(Wih1, 64, 64  + col1, k0);
            WF[4+kf]  = loadBfrag(Wih1, 64, 128 + col1, k0);
            WF[6+kf]  = loadBfrag(Whh1, 64, col1,       k0);
            WF[8+kf]  = loadBfrag(Whh1, 64, 64  + col1, k0);
            WF[10+kf] = loadBfrag(Whh1, 64, 128 + col1, k0);
        }
        BF[0] = splat4(bih1[col1] + bhh1[col1]);
        BF[1] = splat4(bih1[64 + col1] + bhh1[64 + col1]);
        BF[2] = splat4(bih1[128 + col1]);
        BF[3] = splat4(bhh1[128 + col1]);
    } else if (isL2){
        const int c2 = (wv & 1)*16 + lrow;
        #pragma unroll
        for (int kf = 0; kf < 2; ++kf){
            const int k0 = kf*32 + 8*lq;
            WF[0+kf] = loadBfrag(Wih2, 64, c2,      k0);
            WF[2+kf] = loadBfrag(Wih2, 64, 32 + c2, k0);
            WF[4+kf] = loadBfrag(Wih2, 64, 64 + c2, k0);
        }
        WF[6] = loadBfrag(Whh2, 32, c2,      8*lq);
        WF[7] = loadBfrag(Whh2, 32, 32 + c2, 8*lq);
        WF[8] = loadBfrag(Whh2, 32, 64 + c2, 8*lq);
        BF[0] = splat4(bih2[c2] + bhh2[c2]);
        BF[1] = splat4(bih2[32 + c2] + bhh2[32 + c2]);
        BF[2] = splat4(bih2[64 + c2]);
        BF[3] = splat4(bhh2[64 + c2]);
    }

    // x staging (staging pair): 2 floats/thread, 2-phase register hold
    const int u   = (wv & 1)*64 + lane;
    const int xb2 = u >> 5, xk2 = (u & 31)*2;
    const int xo2 = xb2*72 + xk2;
    const float* xld = x + ((size_t)(bbase + xb2) * T_SEQ + 4)*64 + xk2;
    float2 xp0 = {0.f,0.f}, xp1 = {0.f,0.f};
    if (isXW){
        xp0 = *(const float2*)(x + ((size_t)(bbase + xb2) * T_SEQ + 2)*64 + xk2);
        xp1 = *(const float2*)(x + ((size_t)(bbase + xb2) * T_SEQ + 3)*64 + xk2);
    }

    const int fo0 = r4*72 + 8*lq;
    const int go2 = r4*40 + 8*lq;
    const int rgo = lq*72 + (wv & 3)*16 + lrow;   // L1 write addr (L1 waves only use)
    const int h2o = lq*40 + (wv & 1)*16 + lrow;   // L2 write addr

    float hs = 0.f;   // L1: h1 state (batch lq, col rgo) | L2: h2 state (batch lq, col h2o)

    __syncthreads();   // full drain once

// SX = t&3 (x read slot; write slot SX^2), SP = t&1 (RG write / H2 read slot)
#define GSTEP(SX, SP, DO_L1, DO_L2, DO_X, DO_XLD) do{                         \
    if ((DO_X) && isXW){                                                      \
        float2 xn2;                                                           \
        if (DO_XLD){ xn2 = *(const float2*)xld; xld += 64; }                  \
        const unsigned short a0 = f2bf_rnd(xp0.x), a1 = f2bf_rnd(xp0.y);      \
        *(unsigned*)(&XHI[(SX)^2][xo2]) = (unsigned)a0 | ((unsigned)a1 << 16);\
        xp0 = xp1;                                                            \
        if (DO_XLD) xp1 = xn2;                                                \
    }                                                                         \
    if ((DO_L1) && isL1){                                                     \
        frag_ab hhf0, hhf1, hlf0, hlf1, xhf0, xhf1;                           \
        hhf0 = *(const frag_ab*)(&RGhi[(SP)^1][fo0]);                         \
        hhf1 = *(const frag_ab*)(&RGhi[(SP)^1][fo0 + 32]);                    \
        hlf0 = *(const frag_ab*)(&RGlo[(SP)^1][fo0]);                         \
        hlf1 = *(const frag_ab*)(&RGlo[(SP)^1][fo0 + 32]);                    \
        xhf0 = *(const frag_ab*)(&XHI[SX][fo0]);                              \
        xhf1 = *(const frag_ab*)(&XHI[SX][fo0 + 32]);                         \
        frag_cd A0 = BF[0], A1 = BF[1], A2 = BF[2], A3 = BF[3];               \
        A0 = MFMA(xhf0, WF[0], A0); A0 = MFMA(xhf1, WF[1], A0);               \
        A0 = MFMA(hhf0, WF[6], A0); A0 = MFMA(hlf0, WF[6], A0);               \
        A0 = MFMA(hhf1, WF[7], A0); A0 = MFMA(hlf1, WF[7], A0);               \
        A1 = MFMA(xhf0, WF[2], A1); A1 = MFMA(xhf1, WF[3], A1);               \
        A1 = MFMA(hhf0, WF[8], A1); A1 = MFMA(hlf0, WF[8], A1);               \
        A1 = MFMA(hhf1, WF[9], A1); A1 = MFMA(hlf1, WF[9], A1);               \
        A2 = MFMA(xhf0, WF[4], A2); A2 = MFMA(xhf1, WF[5], A2);               \
        A3 = MFMA(hhf0, WF[10], A3); A3 = MFMA(hlf0, WF[10], A3);             \
        A3 = MFMA(hhf1, WF[11], A3); A3 = MFMA(hlf1, WF[11], A3);             \
        const float vR = sel4(A0, lq), vZ = sel4(A1, lq);                     \
        const float vI = sel4(A2, lq), vH = sel4(A3, lq);                     \
        const float rg = sigf(vR), zg = sigf(vZ);                             \
        const float ng = tanhf2(vI + rg*vH);                                  \
        hs = ng + zg*(hs - ng);                                               \
        unsigned short hb, lb; tsplit(hs, hb, lb);                            \
        RGhi[SP][rgo] = hb; RGlo[SP][rgo] = lb;                               \
    }                                                                         \
    if ((DO_L2) && isL2){                                                     \
        frag_ab hhf0, hhf1, g2hf, g2lf;                                       \
        hhf0 = *(const frag_ab*)(&RGhi[(SP)^1][fo0]);                         \
        hhf1 = *(const frag_ab*)(&RGhi[(SP)^1][fo0 + 32]);                    \
        g2hf = *(const frag_ab*)(&H2HI[SP][go2]);                             \
        g2lf = *(const frag_ab*)(&H2LO[SP][go2]);                             \
        frag_cd B0 = BF[0], B1 = BF[1], B2 = BF[2], B3 = BF[3];               \
        B0 = MFMA(hhf0, WF[0], B0); B0 = MFMA(hhf1, WF[1], B0);               \
        B1 = MFMA(hhf0, WF[2], B1); B1 = MFMA(hhf1, WF[3], B1);               \
        B2 = MFMA(hhf0, WF[4], B2); B2 = MFMA(hhf1, WF[5], B2);               \
        B0 = MFMA(g2hf, WF[6], B0); B0 = MFMA(g2lf, WF[6], B0);               \
        B1 = MFMA(g2hf, WF[7], B1); B1 = MFMA(g2lf, WF[7], B1);               \
        B3 = MFMA(g2hf, WF[8], B3); B3 = MFMA(g2lf, WF[8], B3);               \
        const float wR = sel4(B0, lq), wZ = sel4(B1, lq);                     \
        const float wI = sel4(B2, lq), wH = sel4(B3, lq);                     \
        const float rv = sigf(wR), zv = sigf(wZ);                             \
        const float nv = tanhf2(wI + rv*wH);                                  \
        hs = nv + zv*(hs - nv);                                               \
        unsigned short hb, lb; tsplit(hs, hb, lb);                            \
        H2HI[(SP)^1][h2o] = hb; H2LO[(SP)^1][h2o] = lb;                       \
    }                                                                         \
    BAR();                                                                    \
}while(0)

    // phase 0 (L1 + staging; no L2 yet)
    GSTEP(0, 0, true, false, true, true);

    // phases 1..504: 126 iterations x 4 (all ring slots literal)
    #pragma unroll 1
    for (int i = 0; i < 126; ++i){
        GSTEP(1, 1, true, true, true, true);
        GSTEP(2, 0, true, true, true, true);
        GSTEP(3, 1, true, true, true, true);
        GSTEP(0, 0, true, true, true, true);
    }

    // tail phases 505..512
    GSTEP(1, 1, true, true, true,  true);    // 505: loads row 509
    GSTEP(2, 0, true, true, true,  true);    // 506: loads row 510
    GSTEP(3, 1, true, true, true,  true);    // 507: loads row 511
    GSTEP(0, 0, true, true, true,  false);   // 508: write x(510)
    GSTEP(1, 1, true, true, true,  false);   // 509: write x(511)
    GSTEP(2, 0, true, true, false, false);   // 510
    GSTEP(3, 1, true, true, false, false);   // 511
    GSTEP(0, 0, false, true, false, false);  // 512: L2 final step
#undef GSTEP

    // head: h2(511) in H2 slot 1
    if (tid < 128){
        const int r = tid >> 5, c = tid & 31;
        HFIN[r*32 + c] = bf2f(H2HI[1][r*40 + c]) + bf2f(H2LO[1][r*40 + c]);
    }
    __syncthreads();
    if (tid < 64){
        const int b = tid >> 4, f = tid & 15;
        float s = bfc[f];
        #pragma unroll
        for (int k = 0; k < 32; ++k) s += HFIN[b*32 + k] * Wfc[f*32 + k];
        FCS[b*16 + f] = fmaxf(s, 0.f);
    }
    __syncthreads();
    if (tid < 4){
        float o = bout[0];
        #pragma unroll
        for (int f = 0; f < 16; ++f) o += FCS[tid*16 + f] * Wout[f];
        out[bbase + tid] = o;
    }
}

extern "C" void kernel_launch(void* const* d_in, const int* in_sizes, int n_in,
                              void* d_out, int out_size, void* d_ws, size_t ws_size,
                              hipStream_t stream) {
    const float* x    = (const float*)d_in[0];
    const float* Wih1 = (const float*)d_in[1];
    const float* Whh1 = (const float*)d_in[2];
    const float* bih1 = (const float*)d_in[3];
    const float* bhh1 = (const float*)d_in[4];
    const float* Wih2 = (const float*)d_in[5];
    const float* Whh2 = (const float*)d_in[6];
    const float* bih2 = (const float*)d_in[7];
    const float* bhh2 = (const float*)d_in[8];
    const float* Wfc  = (const float*)d_in[9];
    const float* bfc  = (const float*)d_in[10];
    const float* Wout = (const float*)d_in[11];
    const float* bout = (const float*)d_in[12];

    gru_fused8<<<512, 512, 0, stream>>>(x, Wih1, Whh1, bih1, bhh1,
                                        Wih2, Whh2, bih2, bhh2,
                                        Wfc, bfc, Wout, bout, (float*)d_out);
}

// Round 10
// 261.119 us; speedup vs baseline: 4.5387x; 1.2355x over previous
//
#include <hip/hip_runtime.h>
#include <hip/hip_bf16.h>

#define T_SEQ 512

typedef __attribute__((ext_vector_type(8))) short frag_ab;
typedef __attribute__((ext_vector_type(4))) float frag_cd;

static __device__ __forceinline__ unsigned short f2bf_rnd(float f){
    union { float f; unsigned u; } v; v.f = f;
    unsigned r = v.u + 0x7fffu + ((v.u >> 16) & 1u);
    return (unsigned short)(r >> 16);
}
static __device__ __forceinline__ float bf2f(unsigned short h){
    union { unsigned u; float f; } v; v.u = ((unsigned)h) << 16;
    return v.f;
}
static __device__ __forceinline__ void tsplit(float f, unsigned short &hi, unsigned short &lo){
    union { float f; unsigned u; } v; v.f = f;
    const unsigned uh = v.u & 0xFFFF0000u;
    hi = (unsigned short)(uh >> 16);
    union { unsigned u; float f; } w; w.u = uh;
    union { float f; unsigned u; } r; r.f = f - w.f;
    lo = (unsigned short)(r.u >> 16);
}
static __device__ __forceinline__ float sigf(float v){
    return __builtin_amdgcn_rcpf(1.0f + __builtin_amdgcn_exp2f(-1.4426950408889634f * v));
}
static __device__ __forceinline__ float tanhf2(float v){
    return 2.0f * __builtin_amdgcn_rcpf(1.0f + __builtin_amdgcn_exp2f(-2.8853900817779268f * v)) - 1.0f;
}
static __device__ __forceinline__ frag_ab loadBfrag(const float* __restrict__ W, int ldk, int jcol, int k0){
    const float* p = W + jcol * ldk + k0;
    frag_ab r;
    #pragma unroll
    for (int i = 0; i < 8; ++i) r[i] = (short)f2bf_rnd(p[i]);
    return r;
}
static __device__ __forceinline__ float sel4(frag_cd a, int q){
    const float v01 = (q == 0) ? a[0] : a[1];
    const float v23 = (q == 2) ? a[2] : a[3];
    return (q < 2) ? v01 : v23;
}
static __device__ __forceinline__ frag_cd splat4(float v){ return frag_cd{v,v,v,v}; }

#define MFMA(a,b,c) __builtin_amdgcn_mfma_f32_16x16x32_bf16((a),(b),(c),0,0,0)

// Counted barrier: drain LDS only; in-flight global x loads cross the barrier.
#define BAR() asm volatile("s_waitcnt lgkmcnt(0)\ns_barrier" ::: "memory")

// R10 = R9 + h1-lo drop (h1 stored as single rnd-bf16: L1 18->12 MFMA, RGlo
// ring deleted) + bias-as-C-in (no acc-init movs, shorter chains) + setprio(1)
// around MFMA clusters (T5: role-split waves). h2 keeps hi/lo (cheap, output-
// critical). Pre-committed revert if absmax > 3.2e-3: restore L1-hh lo.
__global__ __launch_bounds__(512, 2)
void gru_fused9(const float* __restrict__ x,
                const float* __restrict__ Wih1, const float* __restrict__ Whh1,
                const float* __restrict__ bih1, const float* __restrict__ bhh1,
                const float* __restrict__ Wih2, const float* __restrict__ Whh2,
                const float* __restrict__ bih2, const float* __restrict__ bhh2,
                const float* __restrict__ Wfc,  const float* __restrict__ bfc,
                const float* __restrict__ Wout, const float* __restrict__ bout,
                float* __restrict__ out)
{
    __shared__ __align__(16) unsigned short RGhi[2][288];
    __shared__ __align__(16) unsigned short XHI[4][288];
    __shared__ __align__(16) unsigned short H2HI[2][160], H2LO[2][160];
    __shared__ float HFIN[128];
    __shared__ float FCS[64];

    const int tid  = threadIdx.x;
    const int wv   = tid >> 6;
    const int lane = tid & 63;
    const int lrow = lane & 15;
    const int lq   = lane >> 4;
    const int r4   = lrow & 3;
    const int bbase = blockIdx.x * 4;
    const int hv   = (int)(blockIdx.x & 1);
    const bool isL1 = (wv < 4);
    const bool isL2 = (!isL1) && (((wv >> 1) & 1) == hv);
    const bool isXW = (!isL1) && !isL2;

    for (int i = tid; i < 288; i += 512){ RGhi[1][i] = 0; }
    for (int i = tid; i < 160; i += 512){ H2HI[1][i] = 0; H2LO[1][i] = 0; }

    // prologue x staging: x(0)->slot0, x(1)->slot1 (512 thr x 1 elem)
    {
        const int s = tid >> 8, idx = tid & 255;
        const int b = idx >> 6, k = idx & 63;
        XHI[s][b*72 + k] = f2bf_rnd(x[((size_t)(bbase + b) * T_SEQ + s) * 64 + k]);
    }

    // role-unioned persistent registers
    frag_ab WF[12];
    frag_cd BF[4];

    if (isL1){
        const int col1 = wv*16 + lrow;
        #pragma unroll
        for (int kf = 0; kf < 2; ++kf){
            const int k0 = kf*32 + 8*lq;
            WF[0+kf]  = loadBfrag(Wih1, 64, col1,       k0);
            WF[2+kf]  = loadBfrag(Wih1, 64, 64  + col1, k0);
            WF[4+kf]  = loadBfrag(Wih1, 64, 128 + col1, k0);
            WF[6+kf]  = loadBfrag(Whh1, 64, col1,       k0);
            WF[8+kf]  = loadBfrag(Whh1, 64, 64  + col1, k0);
            WF[10+kf] = loadBfrag(Whh1, 64, 128 + col1, k0);
        }
        BF[0] = splat4(bih1[col1] + bhh1[col1]);
        BF[1] = splat4(bih1[64 + col1] + bhh1[64 + col1]);
        BF[2] = splat4(bih1[128 + col1]);
        BF[3] = splat4(bhh1[128 + col1]);
    } else if (isL2){
        const int c2 = (wv & 1)*16 + lrow;
        #pragma unroll
        for (int kf = 0; kf < 2; ++kf){
            const int k0 = kf*32 + 8*lq;
            WF[0+kf] = loadBfrag(Wih2, 64, c2,      k0);
            WF[2+kf] = loadBfrag(Wih2, 64, 32 + c2, k0);
            WF[4+kf] = loadBfrag(Wih2, 64, 64 + c2, k0);
        }
        WF[6] = loadBfrag(Whh2, 32, c2,      8*lq);
        WF[7] = loadBfrag(Whh2, 32, 32 + c2, 8*lq);
        WF[8] = loadBfrag(Whh2, 32, 64 + c2, 8*lq);
        BF[0] = splat4(bih2[c2] + bhh2[c2]);
        BF[1] = splat4(bih2[32 + c2] + bhh2[32 + c2]);
        BF[2] = splat4(bih2[64 + c2]);
        BF[3] = splat4(bhh2[64 + c2]);
    }

    // x staging (staging pair): 2 floats/thread, 2-phase register hold
    const int u   = (wv & 1)*64 + lane;
    const int xb2 = u >> 5, xk2 = (u & 31)*2;
    const int xo2 = xb2*72 + xk2;
    const float* xld = x + ((size_t)(bbase + xb2) * T_SEQ + 4)*64 + xk2;
    float2 xp0 = {0.f,0.f}, xp1 = {0.f,0.f};
    if (isXW){
        xp0 = *(const float2*)(x + ((size_t)(bbase + xb2) * T_SEQ + 2)*64 + xk2);
        xp1 = *(const float2*)(x + ((size_t)(bbase + xb2) * T_SEQ + 3)*64 + xk2);
    }

    const int fo0 = r4*72 + 8*lq;
    const int go2 = r4*40 + 8*lq;
    const int rgo = lq*72 + (wv & 3)*16 + lrow;
    const int h2o = lq*40 + (wv & 1)*16 + lrow;

    float hs = 0.f;

    __syncthreads();   // full drain once

// SX = t&3 (x read slot; write slot SX^2), SP = t&1 (RG write / H2 read slot)
#define GSTEP(SX, SP, DO_L1, DO_L2, DO_X, DO_XLD) do{                         \
    if ((DO_X) && isXW){                                                      \
        float2 xn2;                                                           \
        if (DO_XLD){ xn2 = *(const float2*)xld; xld += 64; }                  \
        const unsigned short a0 = f2bf_rnd(xp0.x), a1 = f2bf_rnd(xp0.y);      \
        *(unsigned*)(&XHI[(SX)^2][xo2]) = (unsigned)a0 | ((unsigned)a1 << 16);\
        xp0 = xp1;                                                            \
        if (DO_XLD) xp1 = xn2;                                                \
    }                                                                         \
    if ((DO_L1) && isL1){                                                     \
        frag_ab hhf0, hhf1, xhf0, xhf1;                                       \
        hhf0 = *(const frag_ab*)(&RGhi[(SP)^1][fo0]);                         \
        hhf1 = *(const frag_ab*)(&RGhi[(SP)^1][fo0 + 32]);                    \
        xhf0 = *(const frag_ab*)(&XHI[SX][fo0]);                              \
        xhf1 = *(const frag_ab*)(&XHI[SX][fo0 + 32]);                         \
        __builtin_amdgcn_s_setprio(1);                                        \
        frag_cd A0, A1, A2, A3;                                               \
        A0 = MFMA(xhf0, WF[0], BF[0]); A0 = MFMA(xhf1, WF[1], A0);            \
        A0 = MFMA(hhf0, WF[6], A0);    A0 = MFMA(hhf1, WF[7], A0);            \
        A1 = MFMA(xhf0, WF[2], BF[1]); A1 = MFMA(xhf1, WF[3], A1);            \
        A1 = MFMA(hhf0, WF[8], A1);    A1 = MFMA(hhf1, WF[9], A1);            \
        A2 = MFMA(xhf0, WF[4], BF[2]); A2 = MFMA(xhf1, WF[5], A2);            \
        A3 = MFMA(hhf0, WF[10], BF[3]); A3 = MFMA(hhf1, WF[11], A3);          \
        __builtin_amdgcn_s_setprio(0);                                        \
        const float vR = sel4(A0, lq), vZ = sel4(A1, lq);                     \
        const float vI = sel4(A2, lq), vH = sel4(A3, lq);                     \
        const float rg = sigf(vR), zg = sigf(vZ);                             \
        const float ng = tanhf2(vI + rg*vH);                                  \
        hs = ng + zg*(hs - ng);                                               \
        RGhi[SP][rgo] = f2bf_rnd(hs);                                         \
    }                                                                         \
    if ((DO_L2) && isL2){                                                     \
        frag_ab hhf0, hhf1, g2hf, g2lf;                                       \
        hhf0 = *(const frag_ab*)(&RGhi[(SP)^1][fo0]);                         \
        hhf1 = *(const frag_ab*)(&RGhi[(SP)^1][fo0 + 32]);                    \
        g2hf = *(const frag_ab*)(&H2HI[SP][go2]);                             \
        g2lf = *(const frag_ab*)(&H2LO[SP][go2]);                             \
        __builtin_amdgcn_s_setprio(1);                                        \
        frag_cd B0, B1, B2, B3;                                               \
        B0 = MFMA(hhf0, WF[0], BF[0]); B0 = MFMA(hhf1, WF[1], B0);            \
        B0 = MFMA(g2hf, WF[6], B0);    B0 = MFMA(g2lf, WF[6], B0);            \
        B1 = MFMA(hhf0, WF[2], BF[1]); B1 = MFMA(hhf1, WF[3], B1);            \
        B1 = MFMA(g2hf, WF[7], B1);    B1 = MFMA(g2lf, WF[7], B1);            \
        B2 = MFMA(hhf0, WF[4], BF[2]); B2 = MFMA(hhf1, WF[5], B2);            \
        B3 = MFMA(g2hf, WF[8], BF[3]); B3 = MFMA(g2lf, WF[8], B3);            \
        __builtin_amdgcn_s_setprio(0);                                        \
        const float wR = sel4(B0, lq), wZ = sel4(B1, lq);                     \
        const float wI = sel4(B2, lq), wH = sel4(B3, lq);                     \
        const float rv = sigf(wR), zv = sigf(wZ);                             \
        const float nv = tanhf2(wI + rv*wH);                                  \
        hs = nv + zv*(hs - nv);                                               \
        unsigned short hb, lb; tsplit(hs, hb, lb);                            \
        H2HI[(SP)^1][h2o] = hb; H2LO[(SP)^1][h2o] = lb;                       \
    }                                                                         \
    BAR();                                                                    \
}while(0)

    // phase 0 (L1 + staging; no L2 yet)
    GSTEP(0, 0, true, false, true, true);

    // phases 1..504: 126 iterations x 4 (all ring slots literal)
    #pragma unroll 1
    for (int i = 0; i < 126; ++i){
        GSTEP(1, 1, true, true, true, true);
        GSTEP(2, 0, true, true, true, true);
        GSTEP(3, 1, true, true, true, true);
        GSTEP(0, 0, true, true, true, true);
    }

    // tail phases 505..512
    GSTEP(1, 1, true, true, true,  true);    // 505: loads row 509
    GSTEP(2, 0, true, true, true,  true);    // 506: loads row 510
    GSTEP(3, 1, true, true, true,  true);    // 507: loads row 511
    GSTEP(0, 0, true, true, true,  false);   // 508: write x(510)
    GSTEP(1, 1, true, true, true,  false);   // 509: write x(511)
    GSTEP(2, 0, true, true, false, false);   // 510
    GSTEP(3, 1, true, true, false, false);   // 511
    GSTEP(0, 0, false, true, false, false);  // 512: L2 final step
#undef GSTEP

    // head: h2(511) in H2 slot 1
    if (tid < 128){
        const int r = tid >> 5, c = tid & 31;
        HFIN[r*32 + c] = bf2f(H2HI[1][r*40 + c]) + bf2f(H2LO[1][r*40 + c]);
    }
    __syncthreads();
    if (tid < 64){
        const int b = tid >> 4, f = tid & 15;
        float s = bfc[f];
        #pragma unroll
        for (int k = 0; k < 32; ++k) s += HFIN[b*32 + k] * Wfc[f*32 + k];
        FCS[b*16 + f] = fmaxf(s, 0.f);
    }
    __syncthreads();
    if (tid < 4){
        float o = bout[0];
        #pragma unroll
        for (int f = 0; f < 16; ++f) o += FCS[tid*16 + f] * Wout[f];
        out[bbase + tid] = o;
    }
}

extern "C" void kernel_launch(void* const* d_in, const int* in_sizes, int n_in,
                              void* d_out, int out_size, void* d_ws, size_t ws_size,
                              hipStream_t stream) {
    const float* x    = (const float*)d_in[0];
    const float* Wih1 = (const float*)d_in[1];
    const float* Whh1 = (const float*)d_in[2];
    const float* bih1 = (const float*)d_in[3];
    const float* bhh1 = (const float*)d_in[4];
    const float* Wih2 = (const float*)d_in[5];
    const float* Whh2 = (const float*)d_in[6];
    const float* bih2 = (const float*)d_in[7];
    const float* bhh2 = (const float*)d_in[8];
    const float* Wfc  = (const float*)d_in[9];
    const float* bfc  = (const float*)d_in[10];
    const float* Wout = (const float*)d_in[11];
    const float* bout = (const float*)d_in[12];

    gru_fused9<<<512, 512, 0, stream>>>(x, Wih1, Whh1, bih1, bhh1,
                                        Wih2, Whh2, bih2, bhh2,
                                        Wfc, bfc, Wout, bout, (float*)d_out);
}

// Round 12
// 224.424 us; speedup vs baseline: 5.2808x; 1.1635x over previous
//
#include <hip/hip_runtime.h>
#include <hip/hip_bf16.h>

#define T_SEQ 512

typedef __attribute__((ext_vector_type(8))) short frag_ab;
typedef __attribute__((ext_vector_type(4))) float frag_cd;

static __device__ __forceinline__ unsigned short f2bf_rnd(float f){
    union { float f; unsigned u; } v; v.f = f;
    unsigned r = v.u + 0x7fffu + ((v.u >> 16) & 1u);
    return (unsigned short)(r >> 16);
}
static __device__ __forceinline__ float bf2f(unsigned short h){
    union { unsigned u; float f; } v; v.u = ((unsigned)h) << 16;
    return v.f;
}
static __device__ __forceinline__ float sigf(float v){
    return __builtin_amdgcn_rcpf(1.0f + __builtin_amdgcn_exp2f(-1.4426950408889634f * v));
}
static __device__ __forceinline__ float tanhf2(float v){
    return 2.0f * __builtin_amdgcn_rcpf(1.0f + __builtin_amdgcn_exp2f(-2.8853900817779268f * v)) - 1.0f;
}
static __device__ __forceinline__ frag_ab loadBfrag(const float* __restrict__ W, int ldk, int jcol, int k0){
    const float* p = W + jcol * ldk + k0;
    frag_ab r;
    #pragma unroll
    for (int i = 0; i < 8; ++i) r[i] = (short)f2bf_rnd(p[i]);
    return r;
}
static __device__ __forceinline__ frag_cd splat4(float v){ return frag_cd{v,v,v,v}; }

#define MFMA(a,b,c) __builtin_amdgcn_mfma_f32_16x16x32_bf16((a),(b),(c),0,0,0)

// Counted barrier: drain LDS only; in-flight global x loads cross the barrier.
#define BAR() asm volatile("s_waitcnt lgkmcnt(0)\ns_barrier" ::: "memory")

// R12 = R11 with the ROCm bf16 API calls replaced by f2bf_rnd (toolchain has
// no __float2bfloat16_rn). Issue cuts kept:
//  (1) A-frag batch remap: batch = row>>2 -> extracted acc element is literal
//      [0] for every lane; sel4's 12 cndmask + cmps deleted.
//  (2) h2-lo dropped: L2 12->9 MFMA, H2LO ring deleted. (x-lo, h1-lo drops
//      measured zero absmax delta. Pre-committed revert if absmax > 3.2e-3.)
__global__ __launch_bounds__(512, 2)
void gru_fusedB(const float* __restrict__ x,
                const float* __restrict__ Wih1, const float* __restrict__ Whh1,
                const float* __restrict__ bih1, const float* __restrict__ bhh1,
                const float* __restrict__ Wih2, const float* __restrict__ Whh2,
                const float* __restrict__ bih2, const float* __restrict__ bhh2,
                const float* __restrict__ Wfc,  const float* __restrict__ bfc,
                const float* __restrict__ Wout, const float* __restrict__ bout,
                float* __restrict__ out)
{
    __shared__ __align__(16) unsigned short RGhi[2][288];
    __shared__ __align__(16) unsigned short XHI[4][288];
    __shared__ __align__(16) unsigned short H2HI[2][160];
    __shared__ float HFIN[128];
    __shared__ float FCS[64];

    const int tid  = threadIdx.x;
    const int wv   = tid >> 6;
    const int lane = tid & 63;
    const int lrow = lane & 15;
    const int lq   = lane >> 4;
    const int b4   = lrow >> 2;          // A-frag row -> batch (remap)
    const int bbase = blockIdx.x * 4;
    const int hv   = (int)(blockIdx.x & 1);
    const bool isL1 = (wv < 4);
    const bool isL2 = (!isL1) && (((wv >> 1) & 1) == hv);
    const bool isXW = (!isL1) && !isL2;

    for (int i = tid; i < 288; i += 512){ RGhi[1][i] = 0; }
    for (int i = tid; i < 160; i += 512){ H2HI[1][i] = 0; }

    // prologue x staging: x(0)->slot0, x(1)->slot1 (512 thr x 1 elem)
    {
        const int s = tid >> 8, idx = tid & 255;
        const int b = idx >> 6, k = idx & 63;
        XHI[s][b*72 + k] = f2bf_rnd(x[((size_t)(bbase + b) * T_SEQ + s) * 64 + k]);
    }

    // role-unioned persistent registers
    frag_ab WF[12];
    frag_cd BF[4];

    if (isL1){
        const int col1 = wv*16 + lrow;
        #pragma unroll
        for (int kf = 0; kf < 2; ++kf){
            const int k0 = kf*32 + 8*lq;
            WF[0+kf]  = loadBfrag(Wih1, 64, col1,       k0);
            WF[2+kf]  = loadBfrag(Wih1, 64, 64  + col1, k0);
            WF[4+kf]  = loadBfrag(Wih1, 64, 128 + col1, k0);
            WF[6+kf]  = loadBfrag(Whh1, 64, col1,       k0);
            WF[8+kf]  = loadBfrag(Whh1, 64, 64  + col1, k0);
            WF[10+kf] = loadBfrag(Whh1, 64, 128 + col1, k0);
        }
        BF[0] = splat4(bih1[col1] + bhh1[col1]);
        BF[1] = splat4(bih1[64 + col1] + bhh1[64 + col1]);
        BF[2] = splat4(bih1[128 + col1]);
        BF[3] = splat4(bhh1[128 + col1]);
    } else if (isL2){
        const int c2 = (wv & 1)*16 + lrow;
        #pragma unroll
        for (int kf = 0; kf < 2; ++kf){
            const int k0 = kf*32 + 8*lq;
            WF[0+kf] = loadBfrag(Wih2, 64, c2,      k0);
            WF[2+kf] = loadBfrag(Wih2, 64, 32 + c2, k0);
            WF[4+kf] = loadBfrag(Wih2, 64, 64 + c2, k0);
        }
        WF[6] = loadBfrag(Whh2, 32, c2,      8*lq);
        WF[7] = loadBfrag(Whh2, 32, 32 + c2, 8*lq);
        WF[8] = loadBfrag(Whh2, 32, 64 + c2, 8*lq);
        BF[0] = splat4(bih2[c2] + bhh2[c2]);
        BF[1] = splat4(bih2[32 + c2] + bhh2[32 + c2]);
        BF[2] = splat4(bih2[64 + c2]);
        BF[3] = splat4(bhh2[64 + c2]);
    }

    // x staging (staging pair): 2 floats/thread, 2-phase register hold
    const int u   = (wv & 1)*64 + lane;
    const int xb2 = u >> 5, xk2 = (u & 31)*2;
    const int xo2 = xb2*72 + xk2;
    const float* xld = x + ((size_t)(bbase + xb2) * T_SEQ + 4)*64 + xk2;
    float2 xp0 = {0.f,0.f}, xp1 = {0.f,0.f};
    if (isXW){
        xp0 = *(const float2*)(x + ((size_t)(bbase + xb2) * T_SEQ + 2)*64 + xk2);
        xp1 = *(const float2*)(x + ((size_t)(bbase + xb2) * T_SEQ + 3)*64 + xk2);
    }

    const int fo0 = b4*72 + 8*lq;        // A-frag read: batch = row>>2
    const int go2 = b4*40 + 8*lq;
    const int rgo = lq*72 + (wv & 3)*16 + lrow;   // writes unchanged (batch lq)
    const int h2o = lq*40 + (wv & 1)*16 + lrow;

    float hs = 0.f;

    __syncthreads();   // full drain once

// SX = t&3 (x read slot; write slot SX^2), SP = t&1 (RG write / H2 read slot)
#define GSTEP(SX, SP, DO_L1, DO_L2, DO_X, DO_XLD) do{                         \
    if ((DO_X) && isXW){                                                      \
        float2 xn2;                                                           \
        if (DO_XLD){ xn2 = *(const float2*)xld; xld += 64; }                  \
        const unsigned short a0 = f2bf_rnd(xp0.x), a1 = f2bf_rnd(xp0.y);      \
        *(unsigned*)(&XHI[(SX)^2][xo2]) = (unsigned)a0 | ((unsigned)a1 << 16);\
        xp0 = xp1;                                                            \
        if (DO_XLD) xp1 = xn2;                                                \
    }                                                                         \
    if ((DO_L1) && isL1){                                                     \
        frag_ab hhf0, hhf1, xhf0, xhf1;                                       \
        hhf0 = *(const frag_ab*)(&RGhi[(SP)^1][fo0]);                         \
        hhf1 = *(const frag_ab*)(&RGhi[(SP)^1][fo0 + 32]);                    \
        xhf0 = *(const frag_ab*)(&XHI[SX][fo0]);                              \
        xhf1 = *(const frag_ab*)(&XHI[SX][fo0 + 32]);                         \
        __builtin_amdgcn_s_setprio(1);                                        \
        frag_cd A0, A1, A2, A3;                                               \
        A0 = MFMA(xhf0, WF[0], BF[0]); A0 = MFMA(xhf1, WF[1], A0);            \
        A0 = MFMA(hhf0, WF[6], A0);    A0 = MFMA(hhf1, WF[7], A0);            \
        A1 = MFMA(xhf0, WF[2], BF[1]); A1 = MFMA(xhf1, WF[3], A1);            \
        A1 = MFMA(hhf0, WF[8], A1);    A1 = MFMA(hhf1, WF[9], A1);            \
        A2 = MFMA(xhf0, WF[4], BF[2]); A2 = MFMA(xhf1, WF[5], A2);            \
        A3 = MFMA(hhf0, WF[10], BF[3]); A3 = MFMA(hhf1, WF[11], A3);          \
        __builtin_amdgcn_s_setprio(0);                                        \
        const float rg = sigf(A0[0]), zg = sigf(A1[0]);                       \
        const float ng = tanhf2(A2[0] + rg*A3[0]);                            \
        hs = ng + zg*(hs - ng);                                               \
        RGhi[SP][rgo] = f2bf_rnd(hs);                                         \
    }                                                                         \
    if ((DO_L2) && isL2){                                                     \
        frag_ab hhf0, hhf1, g2hf;                                             \
        hhf0 = *(const frag_ab*)(&RGhi[(SP)^1][fo0]);                         \
        hhf1 = *(const frag_ab*)(&RGhi[(SP)^1][fo0 + 32]);                    \
        g2hf = *(const frag_ab*)(&H2HI[SP][go2]);                             \
        __builtin_amdgcn_s_setprio(1);                                        \
        frag_cd B0, B1, B2, B3;                                               \
        B0 = MFMA(hhf0, WF[0], BF[0]); B0 = MFMA(hhf1, WF[1], B0);            \
        B0 = MFMA(g2hf, WF[6], B0);                                           \
        B1 = MFMA(hhf0, WF[2], BF[1]); B1 = MFMA(hhf1, WF[3], B1);            \
        B1 = MFMA(g2hf, WF[7], B1);                                           \
        B2 = MFMA(hhf0, WF[4], BF[2]); B2 = MFMA(hhf1, WF[5], B2);            \
        B3 = MFMA(g2hf, WF[8], BF[3]);                                        \
        __builtin_amdgcn_s_setprio(0);                                        \
        const float rv = sigf(B0[0]), zv = sigf(B1[0]);                       \
        const float nv = tanhf2(B2[0] + rv*B3[0]);                            \
        hs = nv + zv*(hs - nv);                                               \
        H2HI[(SP)^1][h2o] = f2bf_rnd(hs);                                     \
    }                                                                         \
    BAR();                                                                    \
}while(0)

    // phase 0 (L1 + staging; no L2 yet)
    GSTEP(0, 0, true, false, true, true);

    // phases 1..504: 126 iterations x 4 (all ring slots literal)
    #pragma unroll 1
    for (int i = 0; i < 126; ++i){
        GSTEP(1, 1, true, true, true, true);
        GSTEP(2, 0, true, true, true, true);
        GSTEP(3, 1, true, true, true, true);
        GSTEP(0, 0, true, true, true, true);
    }

    // tail phases 505..512
    GSTEP(1, 1, true, true, true,  true);    // 505: loads row 509
    GSTEP(2, 0, true, true, true,  true);    // 506: loads row 510
    GSTEP(3, 1, true, true, true,  true);    // 507: loads row 511
    GSTEP(0, 0, true, true, true,  false);   // 508: write x(510)
    GSTEP(1, 1, true, true, true,  false);   // 509: write x(511)
    GSTEP(2, 0, true, true, false, false);   // 510
    GSTEP(3, 1, true, true, false, false);   // 511
    GSTEP(0, 0, false, true, false, false);  // 512: L2 final step
#undef GSTEP

    // head: h2(511) in H2 slot 1
    if (tid < 128){
        const int r = tid >> 5, c = tid & 31;
        HFIN[r*32 + c] = bf2f(H2HI[1][r*40 + c]);
    }
    __syncthreads();
    if (tid < 64){
        const int b = tid >> 4, f = tid & 15;
        float s = bfc[f];
        #pragma unroll
        for (int k = 0; k < 32; ++k) s += HFIN[b*32 + k] * Wfc[f*32 + k];
        FCS[b*16 + f] = fmaxf(s, 0.f);
    }
    __syncthreads();
    if (tid < 4){
        float o = bout[0];
        #pragma unroll
        for (int f = 0; f < 16; ++f) o += FCS[tid*16 + f] * Wout[f];
        out[bbase + tid] = o;
    }
}

extern "C" void kernel_launch(void* const* d_in, const int* in_sizes, int n_in,
                              void* d_out, int out_size, void* d_ws, size_t ws_size,
                              hipStream_t stream) {
    const float* x    = (const float*)d_in[0];
    const float* Wih1 = (const float*)d_in[1];
    const float* Whh1 = (const float*)d_in[2];
    const float* bih1 = (const float*)d_in[3];
    const float* bhh1 = (const float*)d_in[4];
    const float* Wih2 = (const float*)d_in[5];
    const float* Whh2 = (const float*)d_in[6];
    const float* bih2 = (const float*)d_in[7];
    const float* bhh2 = (const float*)d_in[8];
    const float* Wfc  = (const float*)d_in[9];
    const float* bfc  = (const float*)d_in[10];
    const float* Wout = (const float*)d_in[11];
    const float* bout = (const float*)d_in[12];

    gru_fusedB<<<512, 512, 0, stream>>>(x, Wih1, Whh1, bih1, bhh1,
                                        Wih2, Whh2, bih2, bhh2,
                                        Wfc, bfc, Wout, bout, (float*)d_out);
}